// Round 8
// baseline (607.718 us; speedup 1.0000x reference)
//
#include <hip/hip_runtime.h>
#include <stdint.h>

// Problem constants (match reference)
#define USER_N 100000
#define ITEM_N 50000
#define TAG_N  20000
#define NN (USER_N + ITEM_N)   // 150000 interaction-graph nodes
#define MM (ITEM_N + TAG_N)    // 70000 tag-graph nodes
#define DD 64
#define NT_ROWS (NN + MM + USER_N)   // 320000 merged rows (adj | tag | soc)

// Bucket scatter geometry (R16)
#define BSH 10
#define BROWS (1 << BSH)       // 1024 rows per bucket
#define NBKT0 147              // ceil(NN/1024)           — round 0 (adj)
#define NBKT1 167              // ceil((MM+USER_N)/1024)  — round 1 (tag+soc)
#define BCAP 20                // LDS staged records per bucket (stride 160 B: 4 bank phases)
#define BIN_BLOCKS 512         // 2 blocks/CU (wave-limit) -> overlap hides barrier drains
#define BIN_THREADS 1024
#define LS_THREADS 512
#define OCAP 65536             // overflow list capacity

// ---------------------------------------------------------------------------
// JAX threefry2x32 (20 rounds), bit-exact (verified: R1 absmax 0.0).
// ---------------------------------------------------------------------------
__host__ __device__ __forceinline__ void tf2x32(uint32_t k0, uint32_t k1,
                                                uint32_t x0, uint32_t x1,
                                                uint32_t* o0, uint32_t* o1) {
  uint32_t ks2 = k0 ^ k1 ^ 0x1BD11BDAu;
#define ROTL32(v, d) (((v) << (d)) | ((v) >> (32 - (d))))
#define TF_RND(d) { x0 += x1; x1 = ROTL32(x1, d); x1 ^= x0; }
  x0 += k0; x1 += k1;
  TF_RND(13) TF_RND(15) TF_RND(26) TF_RND(6)
  x0 += k1;  x1 += ks2 + 1u;
  TF_RND(17) TF_RND(29) TF_RND(16) TF_RND(24)
  x0 += ks2; x1 += k0 + 2u;
  TF_RND(13) TF_RND(15) TF_RND(26) TF_RND(6)
  x0 += k0;  x1 += k1 + 3u;
  TF_RND(17) TF_RND(29) TF_RND(16) TF_RND(24)
  x0 += k1;  x1 += ks2 + 4u;
  TF_RND(13) TF_RND(15) TF_RND(26) TF_RND(6)
  x0 += ks2; x1 += k0 + 5u;
  *o0 = x0; *o1 = x1;
#undef TF_RND
#undef ROTL32
}

// keep-mask(e; key), bit-exact vs jax uniform+floor (e = LOCAL per-graph idx)
__device__ __forceinline__ float drop_mask(uint32_t e, uint32_t k0, uint32_t k1) {
  uint32_t o0, o1;
  tf2x32(k0, k1, 0u, e, &o0, &o1);
  uint32_t bits = o0 ^ o1;
  float u = __uint_as_float((bits >> 9) | 0x3F800000u) - 1.0f;
  return floorf(u + 0.9f);
}

// bf16 helpers: RNE pack, exact shl unpack
__device__ __forceinline__ uint32_t f2bf(float f) {
  uint32_t u = __float_as_uint(f);
  return (u + 0x7fffu + ((u >> 16) & 1u)) >> 16;
}
__device__ __forceinline__ float bflo(uint32_t u) { return __uint_as_float(u << 16); }
__device__ __forceinline__ float bfhi(uint32_t u) { return __uint_as_float(u & 0xffff0000u); }

// ---------------------------------------------------------------------------
// CSR build (R16 = R15 + occupancy/bank fixes): R15's bin showed occ 19.5%
// (grid 128 on 256 CUs, 1 block/CU -> serial batch chain exposed) and 1.86M
// LDS bank conflicts (BCAP=16 -> 128 B bucket stride -> equal fill-index t
// of ALL buckets in one bank). R16: 512 blocks (2/CU, overlap), BSH=10
// (147/167 buckets -> 27 KB LDS, 2 blocks/CU fit), BCAP=20 (160 B stride,
// 4 bank phases). Full-line invariant kept: aligned 64 B 8-record flushes;
// overflow diverts to bounded ofl; tails pad with sentinels.
// ---------------------------------------------------------------------------

// prep: bucket stage cursors at fixed bases; zero counts; rp[NT_ROWS]=totE.
__global__ void prep_kernel(int* __restrict__ bcur, int* __restrict__ bcnt,
                            int* __restrict__ ocnt, int* __restrict__ rp,
                            int cap0, int cap1, int totE) {
  int t = threadIdx.x;
  if (t < NBKT0) bcur[t] = t * cap0;
  else if (t < NBKT0 + NBKT1) bcur[t] = (t - NBKT0) * cap1;
  if (t < NBKT0 + NBKT1) bcnt[t] = 0;
  if (t == 0) { ocnt[0] = 0; ocnt[1] = 0; rp[NT_ROWS] = totE; }
}

// Bucket bin with fused threefry. Edge index e is LOCAL to this round:
// primary graph (adj | tag) for e < nPrim, secondary (soc) after, with
// secondary rows offset by rowOff2 in this round's local row space.
__global__ __launch_bounds__(BIN_THREADS) void bin_kernel(
    const int* __restrict__ pr, const int* __restrict__ pc, const float* __restrict__ pv,
    const int* __restrict__ sr, const int* __restrict__ scc, const float* __restrict__ sv,
    int* __restrict__ bcur, int* __restrict__ bcnt, int* __restrict__ ocnt,
    int2* __restrict__ ofl, int* __restrict__ obkt,
    int2* __restrict__ stage, int cap,
    int nPrim, int nTot, int rowOff2, int bktBase, int nBkt,
    uint32_t pa0, uint32_t pa1, uint32_t pb0, uint32_t pb1,
    uint32_t sa0, uint32_t sa1, uint32_t sb0, uint32_t sb1) {
  __shared__ __align__(16) int2 buf[NBKT1][BCAP];
  __shared__ int fill[NBKT1];
  __shared__ int lcnt[NBKT1];
  int tid = threadIdx.x;
  for (int b = tid; b < NBKT1; b += BIN_THREADS) { fill[b] = 0; lcnt[b] = 0; }
  __syncthreads();
  int per = (nTot + (int)gridDim.x - 1) / (int)gridDim.x;
  int e0 = blockIdx.x * per;
  int e1 = e0 + per; if (e1 > nTot) e1 = nTot;
  const float SC = (float)(1.0 / 0.9);
  for (int base = e0; base < e1; base += BIN_THREADS) {
    int e = base + tid;
    if (e < e1) {
      int j, c; float v; uint32_t le, k00, k01, k10, k11;
      if (e < nPrim) {
        le = (uint32_t)e;
        j = __builtin_nontemporal_load(&pr[e]);
        c = __builtin_nontemporal_load(&pc[e]);
        v = __builtin_nontemporal_load(&pv[e]);
        k00 = pa0; k01 = pa1; k10 = pb0; k11 = pb1;
      } else {
        le = (uint32_t)(e - nPrim);
        j = rowOff2 + __builtin_nontemporal_load(&sr[e - nPrim]);
        c = __builtin_nontemporal_load(&scc[e - nPrim]);
        v = __builtin_nontemporal_load(&sv[e - nPrim]);
        k00 = sa0; k01 = sa1; k10 = sb0; k11 = sb1;
      }
      uint32_t w = f2bf(v * drop_mask(le, k00, k01) * SC) |
                   (f2bf(v * drop_mask(le, k10, k11) * SC) << 16);
      int lb = j >> BSH;
      atomicAdd(&lcnt[lb], 1);
      int2 m = make_int2(c | ((j & (BROWS - 1)) << 18), (int)w);
      int t = atomicAdd(&fill[lb], 1);
      if (t < BCAP) buf[lb][t] = m;
      else {
        int oi = atomicAdd(ocnt, 1);
        if (oi < OCAP) { ofl[oi] = m; obkt[oi] = bktBase + lb; }
      }
    }
    __syncthreads();
    if (tid < nBkt) {
      int f = fill[tid]; if (f > BCAP) f = BCAP;
      int ng = f >> 3;
      if (ng) {
        int n = ng << 3;
        int pos = atomicAdd(&bcur[bktBase + tid], n);
        int limit = (tid + 1) * cap;
        if (pos + n <= limit) {
          int4* dst = (int4*)(stage + pos);
          const int4* src = (const int4*)&buf[tid][0];
          for (int g = 0; g < (ng << 2); ++g) dst[g] = src[g];
        } else {
          for (int k = pos; k < limit; ++k) stage[k] = make_int2(-1, 0);
          for (int q = 0; q < n; ++q) {
            int oi = atomicAdd(ocnt, 1);
            if (oi < OCAP) { ofl[oi] = buf[tid][q]; obkt[oi] = bktBase + tid; }
          }
        }
        int rem = f & 7;
        for (int q = 0; q < rem; ++q) buf[tid][q] = buf[tid][n + q];
        fill[tid] = rem;
      }
    }
    __syncthreads();
  }
  // tail: pad to a full 64 B group with sentinels (skipped downstream)
  if (tid < nBkt) {
    int f = fill[tid]; if (f > BCAP) f = BCAP;
    if (f) {
      for (int q = f; q < 8; ++q) buf[tid][q] = make_int2(-1, 0);
      int pos = atomicAdd(&bcur[bktBase + tid], 8);
      int limit = (tid + 1) * cap;
      if (pos + 8 <= limit) {
        int4* dst = (int4*)(stage + pos);
        const int4* src = (const int4*)&buf[tid][0];
        for (int g = 0; g < 4; ++g) dst[g] = src[g];
      } else {
        for (int k = pos; k < limit; ++k) stage[k] = make_int2(-1, 0);
        for (int q = 0; q < f; ++q) {
          int oi = atomicAdd(ocnt, 1);
          if (oi < OCAP) { ofl[oi] = buf[tid][q]; obkt[oi] = bktBase + tid; }
        }
      }
    }
    // publish real count once per bucket per block
    if (lcnt[tid]) atomicAdd(&bcnt[bktBase + tid], lcnt[tid]);
  }
}

// Local sort: one block per bucket. Pass 1: histogram rows (LDS), prefix
// scan, write rp. Pass 2: place records at final CSR positions. All rec
// writes confined to this bucket's contiguous region (full-line coalesce).
__global__ __launch_bounds__(LS_THREADS) void localsort_kernel(
    int* __restrict__ rp, const int* __restrict__ bcnt,
    const int* __restrict__ bcur, const int* __restrict__ ocnt,
    const int2* __restrict__ ofl, const int* __restrict__ obkt,
    const int2* __restrict__ stage, int2* __restrict__ rec,
    int rowStart, int rowEnd, int eBase, int bktBase, int cap) {
  __shared__ int cur[BROWS];
  __shared__ int red[LS_THREADS];
  int tid = threadIdx.x, lb = blockIdx.x;
  // bucket base = eBase + prefix(bcnt)
  int ps = 0;
  for (int b = tid; b < lb; b += LS_THREADS) ps += bcnt[bktBase + b];
  red[tid] = ps;
  for (int off = LS_THREADS / 2; off > 0; off >>= 1) {
    __syncthreads();
    if (tid < off) red[tid] += red[tid + off];
  }
  __syncthreads();
  int base = eBase + red[0];
  cur[tid] = 0; cur[tid + LS_THREADS] = 0;
  __syncthreads();
  int sbase = lb * cap;
  int send = bcur[bktBase + lb];
  int slim = sbase + cap; if (send > slim) send = slim;
  int nst = send - sbase;
  for (int i = tid; i < nst; i += LS_THREADS) {
    int mx = stage[sbase + i].x;
    if (mx >= 0) atomicAdd(&cur[((uint32_t)mx) >> 18], 1);
  }
  int oc = *ocnt; if (oc > OCAP) oc = OCAP;
  for (int i = tid; i < oc; i += LS_THREADS)
    if (obkt[i] == bktBase + lb) atomicAdd(&cur[((uint32_t)ofl[i].x) >> 18], 1);
  __syncthreads();
  // BROWS-element exclusive scan (pairs per thread)
  int c0 = cur[2 * tid], c1 = cur[2 * tid + 1];
  int pairs = c0 + c1;
  red[tid] = pairs;
  __syncthreads();
  for (int off = 1; off < LS_THREADS; off <<= 1) {
    int v = (tid >= off) ? red[tid - off] : 0;
    __syncthreads();
    red[tid] += v;
    __syncthreads();
  }
  int excl = red[tid] - pairs;
  int r0 = rowStart + (lb << BSH);
  int r = r0 + 2 * tid;
  int p0 = base + excl, p1 = base + excl + c0;
  if (r < rowEnd) rp[r] = p0;
  if (r + 1 < rowEnd) rp[r + 1] = p1;
  __syncthreads();
  cur[2 * tid] = p0; cur[2 * tid + 1] = p1;
  __syncthreads();
  // pass 2: place
  for (int i = tid; i < nst; i += LS_THREADS) {
    int2 m = stage[sbase + i];
    if (m.x >= 0) {
      int pos = atomicAdd(&cur[((uint32_t)m.x) >> 18], 1);
      rec[pos] = make_int2((m.x & 0x3FFFF) * DD, m.y);
    }
  }
  for (int i = tid; i < oc; i += LS_THREADS) {
    if (obkt[i] == bktBase + lb) {
      int2 m = ofl[i];
      int pos = atomicAdd(&cur[((uint32_t)m.x) >> 18], 1);
      rec[pos] = make_int2((m.x & 0x3FFFF) * DD, m.y);
    }
  }
}

// ---------------------------------------------------------------------------
// Gather SpMM core, BATCHED BRANCH-FREE subgroup-per-row (R11): per 8-edge
// batch, load 8 recs, then issue all 8 feature loads with no intervening
// branches (dropped edges contribute exact 0*x), accumulate into 2
// interleaved accumulator sets. ~8 feature loads in flight per subgroup.
// ---------------------------------------------------------------------------
#define FMA8(c0, c1, v, q) { \
    c0.x += v * bflo(q.x); c0.y += v * bfhi(q.x); \
    c0.z += v * bflo(q.y); c0.w += v * bfhi(q.y); \
    c1.x += v * bflo(q.z); c1.y += v * bfhi(q.z); \
    c1.z += v * bflo(q.w); c1.w += v * bfhi(q.w); }

template <int VS>
__device__ __forceinline__ void gather_sub(int s0, int s1, const int2* __restrict__ rec,
                                           const ushort* __restrict__ src,
                                           int fl, float4& A0, float4& A1) {
  float4 a0 = make_float4(0.f, 0.f, 0.f, 0.f);
  float4 a1 = make_float4(0.f, 0.f, 0.f, 0.f);
  float4 b0 = make_float4(0.f, 0.f, 0.f, 0.f);
  float4 b1 = make_float4(0.f, 0.f, 0.f, 0.f);
  const ushort* sl = src + fl * 8;   // this lane's 16 B slice base
  int i = s0;
  for (; i + 8 <= s1; i += 8) {
    long long r[8];
    uint4 q[8];
#pragma unroll
    for (int u = 0; u < 8; ++u)
      r[u] = __builtin_nontemporal_load((const long long*)(rec + i + u));
#pragma unroll
    for (int u = 0; u < 8; ++u)
      q[u] = *(const uint4*)(sl + (uint32_t)r[u]);
#pragma unroll
    for (int u = 0; u < 8; ++u) {
      uint32_t w = (uint32_t)((unsigned long long)r[u] >> 32);
      float v = VS ? bfhi(w) : bflo(w);
      if (u & 1) { FMA8(b0, b1, v, q[u]) } else { FMA8(a0, a1, v, q[u]) }
    }
  }
  if (i + 4 <= s1) {
    long long r[4];
    uint4 q[4];
#pragma unroll
    for (int u = 0; u < 4; ++u)
      r[u] = __builtin_nontemporal_load((const long long*)(rec + i + u));
#pragma unroll
    for (int u = 0; u < 4; ++u)
      q[u] = *(const uint4*)(sl + (uint32_t)r[u]);
#pragma unroll
    for (int u = 0; u < 4; ++u) {
      uint32_t w = (uint32_t)((unsigned long long)r[u] >> 32);
      float v = VS ? bfhi(w) : bflo(w);
      if (u & 1) { FMA8(b0, b1, v, q[u]) } else { FMA8(a0, a1, v, q[u]) }
    }
    i += 4;
  }
  for (; i < s1; ++i) {
    long long rr = __builtin_nontemporal_load((const long long*)(rec + i));
    uint4 q = *(const uint4*)(sl + (uint32_t)rr);
    uint32_t w = (uint32_t)((unsigned long long)rr >> 32);
    float v = VS ? bfhi(w) : bflo(w);
    FMA8(a0, a1, v, q)
  }
  A0 = make_float4(a0.x + b0.x, a0.y + b0.y, a0.z + b0.z, a0.w + b0.w);
  A1 = make_float4(a1.x + b1.x, a1.y + b1.y, a1.z + b1.z, a1.w + b1.w);
}

__device__ __forceinline__ float4 lk4(float4 x) {
  x.x = x.x >= 0.0f ? x.x : 0.5f * x.x;
  x.y = x.y >= 0.0f ? x.y : 0.5f * x.y;
  x.z = x.z >= 0.0f ? x.z : 0.5f * x.z;
  x.w = x.w >= 0.0f ? x.w : 0.5f * x.w;
  return x;
}

__device__ __forceinline__ uint4 pack8(float4 a, float4 b) {
  uint4 p;
  p.x = f2bf(a.x) | (f2bf(a.y) << 16);
  p.y = f2bf(a.z) | (f2bf(a.w) << 16);
  p.z = f2bf(b.x) | (f2bf(b.y) << 16);
  p.w = f2bf(b.z) | (f2bf(b.w) << 16);
  return p;
}

// Mega gather; grid covers NN rows (+TAG_N virtual rows when WITHTAG).
// r < NN:  o = leaky(adj) + (r<USER ? leaky(soc) : leaky(tag item row))
//   FINAL=false: latOut(bf16) = o ; FINAL=true: acc(f32) += f32(lat[r]) + o
// r >= NN (WITHTAG only): rr = r-NN; tgOut[rr] = leaky(tag row ITEM_N+rr)
// Tag source region = lat + USER_N*DD is CONTIGUOUS [items][tags] by layout.
template <int VS, bool FINAL, bool WITHTAG>
__global__ void gather_mega_kernel(
    const int* __restrict__ arp, const int2* __restrict__ arec,
    const int* __restrict__ srp, const int2* __restrict__ srec,
    const int* __restrict__ trp, const int2* __restrict__ trec,
    const ushort* __restrict__ lat,   // NN x 64 bf16 (tag rows follow it)
    ushort* __restrict__ latOut, ushort* __restrict__ tgOut,
    float* __restrict__ acc) {
  int r = (blockIdx.x * blockDim.x + threadIdx.x) >> 3;
  int fl = threadIdx.x & 7;
  if (WITHTAG && r >= NN) {
    int rr = r - NN;
    if (rr >= TAG_N) return;
    int tr = rr + ITEM_N;
    float4 a0, a1;
    gather_sub<VS>(trp[tr], trp[tr + 1], trec, lat + (size_t)USER_N * DD, fl, a0, a1);
    ((uint4*)(tgOut + (size_t)rr * DD))[fl] = pack8(lk4(a0), lk4(a1));
    return;
  }
  if (r >= NN) return;
  float4 t0, t1, b0, b1;
  gather_sub<VS>(arp[r], arp[r + 1], arec, lat, fl, t0, t1);
  if (r < USER_N) {
    gather_sub<VS>(srp[r], srp[r + 1], srec, lat, fl, b0, b1);
  } else {
    int tr = r - USER_N;
    gather_sub<VS>(trp[tr], trp[tr + 1], trec, lat + (size_t)USER_N * DD, fl, b0, b1);
  }
  t0 = lk4(t0); t1 = lk4(t1); b0 = lk4(b0); b1 = lk4(b1);
  float4 o0 = make_float4(t0.x + b0.x, t0.y + b0.y, t0.z + b0.z, t0.w + b0.w);
  float4 o1 = make_float4(t1.x + b1.x, t1.y + b1.y, t1.z + b1.z, t1.w + b1.w);
  if (FINAL) {
    uint4 l = ((const uint4*)(lat + (size_t)r * DD))[fl];
    float4* ap = (float4*)(acc + (size_t)r * DD);
    float4 v0 = ap[fl * 2], v1 = ap[fl * 2 + 1];
    v0.x += bflo(l.x) + o0.x; v0.y += bfhi(l.x) + o0.y;
    v0.z += bflo(l.y) + o0.z; v0.w += bfhi(l.y) + o0.w;
    v1.x += bflo(l.z) + o1.x; v1.y += bfhi(l.z) + o1.y;
    v1.z += bflo(l.w) + o1.z; v1.w += bfhi(l.w) + o1.w;
    ap[fl * 2] = v0; ap[fl * 2 + 1] = v1;
  } else {
    ((uint4*)(latOut + (size_t)r * DD))[fl] = pack8(o0, o1);
  }
}

// acc(f32) = lat0 = concat(u, i); lat0bf = bf16(lat0); tEmbf = bf16(tEmbeds)
__global__ void init_kernel(const float4* __restrict__ u, const float4* __restrict__ it,
                            const float4* __restrict__ tE,
                            float4* __restrict__ acc, ushort4* __restrict__ lat0bf,
                            ushort4* __restrict__ tEmbf) {
  int idx = blockIdx.x * blockDim.x + threadIdx.x;  // NN*16 + TAG_N*16 float4s
  const int uN = USER_N * 16, nN = NN * 16;
  if (idx < nN) {
    float4 v = (idx < uN) ? u[idx] : it[idx - uN];
    acc[idx] = v;
    ushort4 h;
    h.x = (ushort)f2bf(v.x); h.y = (ushort)f2bf(v.y);
    h.z = (ushort)f2bf(v.z); h.w = (ushort)f2bf(v.w);
    lat0bf[idx] = h;
  } else if (idx < nN + TAG_N * 16) {
    int j = idx - nN;
    float4 v = tE[j];
    ushort4 h;
    h.x = (ushort)f2bf(v.x); h.y = (ushort)f2bf(v.y);
    h.z = (ushort)f2bf(v.z); h.w = (ushort)f2bf(v.w);
    tEmbf[j] = h;
  }
}

extern "C" void kernel_launch(void* const* d_in, const int* in_sizes, int n_in,
                              void* d_out, int out_size, void* d_ws, size_t ws_size,
                              hipStream_t stream) {
  const float* uE    = (const float*)d_in[0];
  const float* iE    = (const float*)d_in[1];
  const float* tEm   = (const float*)d_in[2];
  const int*   adj_r = (const int*)d_in[3];
  const int*   adj_c = (const int*)d_in[4];
  const float* adj_v = (const float*)d_in[5];
  const int*   tag_r = (const int*)d_in[6];
  const int*   tag_c = (const int*)d_in[7];
  const float* tag_v = (const float*)d_in[8];
  const int*   soc_r = (const int*)d_in[9];
  const int*   soc_c = (const int*)d_in[10];
  const float* soc_v = (const float*)d_in[11];
  const int nAdj = in_sizes[5], nTag = in_sizes[8], nSoc = in_sizes[11];
  const int totE = nAdj + nTag + nSoc;

  float* acc = (float*)d_out;

  // Workspace (~64 MB live). bf16 regions: [lat0 items][tEmbf] and
  // [lat1][tg1bf] contiguous (tag-gather single-base requirement).
  // Build-phase alias: stage -> lat1bf region (dead until mega0).
  ushort* lat0bf = (ushort*)d_ws;                  // NN*DD bf16
  ushort* tEmbf  = lat0bf + (size_t)NN * DD;       // TAG_N*DD (follows lat0!)
  ushort* lat1bf = tEmbf  + (size_t)TAG_N * DD;    // NN*DD
  ushort* tg1bf  = lat1bf + (size_t)NN * DD;       // TAG_N*DD (follows lat1!)
  int2* stage    = (int2*)lat1bf;                  // alias (dead until mega0)
  const int stageRecs = (int)(((size_t)(NN + TAG_N) * DD * sizeof(ushort)) / sizeof(int2));
  const int cap0 = (stageRecs / NBKT0) & ~7;       // 18496
  const int cap1 = (stageRecs / NBKT1) & ~7;       // 16280
  int2* rec  = (int2*)(tg1bf + (size_t)TAG_N * DD);   // totE {col*DD, pk}
  int2* ofl  = rec + totE;                         // OCAP overflow recs
  int*  ip   = (int*)(ofl + OCAP);
  int* obkt  = ip;  ip += OCAP;
  int* rp    = ip;  ip += NT_ROWS + 1;
  int* bcur  = ip;  ip += NBKT0 + NBKT1;
  int* bcnt  = ip;  ip += NBKT0 + NBKT1;
  int* ocnt  = ip;  ip += 2;

  // fold_in(key(42), j) for j=0..5 (host-side, deterministic)
  uint32_t kk[6][2];
  for (uint32_t j = 0; j < 6; ++j) tf2x32(0u, 42u, 0u, j, &kk[j][0], &kk[j][1]);

  const int thr = 256;
#define CDIV(a, b) (((a) + (b) - 1) / (b))

  // ---- CSR build: prep + 2x(bin + localsort) = 5 dispatches ----
  prep_kernel<<<1, 1024, 0, stream>>>(bcur, bcnt, ocnt, rp, cap0, cap1, totE);
  // round 0: adj rows -> local rows [0, NN), edges [0, nAdj)
  bin_kernel<<<BIN_BLOCKS, BIN_THREADS, 0, stream>>>(
      adj_r, adj_c, adj_v, adj_r, adj_c, adj_v,   // secondary unused
      bcur, bcnt, &ocnt[0], ofl, obkt, stage, cap0,
      nAdj, nAdj, 0, 0, NBKT0,
      kk[0][0], kk[0][1], kk[3][0], kk[3][1], 0u, 0u, 0u, 0u);
  localsort_kernel<<<NBKT0, LS_THREADS, 0, stream>>>(
      rp, bcnt, bcur, &ocnt[0], ofl, obkt, stage, rec, 0, NN, 0, 0, cap0);
  // round 1: tag (local rows [0,MM)) + soc (local rows [MM, MM+USER_N))
  bin_kernel<<<BIN_BLOCKS, BIN_THREADS, 0, stream>>>(
      tag_r, tag_c, tag_v, soc_r, soc_c, soc_v,
      bcur, bcnt, &ocnt[1], ofl, obkt, stage, cap1,
      nTag, nTag + nSoc, MM, NBKT0, NBKT1,
      kk[1][0], kk[1][1], kk[4][0], kk[4][1],
      kk[2][0], kk[2][1], kk[5][0], kk[5][1]);
  localsort_kernel<<<NBKT1, LS_THREADS, 0, stream>>>(
      rp, bcnt, bcur, &ocnt[1], ofl, obkt, stage, rec, NN, NT_ROWS, nAdj, NBKT0, cap1);

  // ---- init: acc = lat0 (f32); lat0bf, tEmbf (bf16 gather sources) ----
  init_kernel<<<CDIV((NN + TAG_N) * 16, thr), thr, 0, stream>>>(
      (const float4*)uE, (const float4*)iE, (const float4*)tEm,
      (float4*)acc, (ushort4*)lat0bf, (ushort4*)tEmbf);

  // ---- layer 0 (tag-node rows fused into the same launch) ----
  const int* arp = rp;
  const int* trp = rp + NN;
  const int* srp = rp + NN + MM;
  gather_mega_kernel<0, false, true><<<CDIV((NN + TAG_N) * 8, thr), thr, 0, stream>>>(
      arp, rec, srp, rec, trp, rec, lat0bf, lat1bf, tg1bf, nullptr);

  // ---- layer 1 ----
  gather_mega_kernel<1, true, false><<<CDIV(NN * 8, thr), thr, 0, stream>>>(
      arp, rec, srp, rec, trp, rec, lat1bf, nullptr, nullptr, acc);
#undef CDIV
}

// Round 9
// 419.169 us; speedup vs baseline: 1.4498x; 1.4498x over previous
//
#include <hip/hip_runtime.h>
#include <stdint.h>

// Problem constants (match reference)
#define USER_N 100000
#define ITEM_N 50000
#define TAG_N  20000
#define NN (USER_N + ITEM_N)   // 150000 interaction-graph nodes
#define MM (ITEM_N + TAG_N)    // 70000 tag-graph nodes
#define DD 64
#define NT_ROWS (NN + MM + USER_N)   // 320000 merged rows (adj | tag | soc)

// Counting-sort geometry (R17)
#define BSH 10
#define BROWS (1 << BSH)       // 1024 rows per bucket
#define NBKT0 147              // ceil(NN/1024)           — round 0 (adj)
#define NBKT1 167              // ceil((MM+USER_N)/1024)  — round 1 (tag+soc)
#define NBKT (NBKT0 + NBKT1)   // 314
#define SLICES 512             // edge slices (bin/hist blocks) per round

// ---------------------------------------------------------------------------
// JAX threefry2x32 (20 rounds), bit-exact (verified: R1 absmax 0.0).
// ---------------------------------------------------------------------------
__host__ __device__ __forceinline__ void tf2x32(uint32_t k0, uint32_t k1,
                                                uint32_t x0, uint32_t x1,
                                                uint32_t* o0, uint32_t* o1) {
  uint32_t ks2 = k0 ^ k1 ^ 0x1BD11BDAu;
#define ROTL32(v, d) (((v) << (d)) | ((v) >> (32 - (d))))
#define TF_RND(d) { x0 += x1; x1 = ROTL32(x1, d); x1 ^= x0; }
  x0 += k0; x1 += k1;
  TF_RND(13) TF_RND(15) TF_RND(26) TF_RND(6)
  x0 += k1;  x1 += ks2 + 1u;
  TF_RND(17) TF_RND(29) TF_RND(16) TF_RND(24)
  x0 += ks2; x1 += k0 + 2u;
  TF_RND(13) TF_RND(15) TF_RND(26) TF_RND(6)
  x0 += k0;  x1 += k1 + 3u;
  TF_RND(17) TF_RND(29) TF_RND(16) TF_RND(24)
  x0 += k1;  x1 += ks2 + 4u;
  TF_RND(13) TF_RND(15) TF_RND(26) TF_RND(6)
  x0 += ks2; x1 += k0 + 5u;
  *o0 = x0; *o1 = x1;
#undef TF_RND
#undef ROTL32
}

// keep-mask(e; key), bit-exact vs jax uniform+floor (e = LOCAL per-graph idx)
__device__ __forceinline__ float drop_mask(uint32_t e, uint32_t k0, uint32_t k1) {
  uint32_t o0, o1;
  tf2x32(k0, k1, 0u, e, &o0, &o1);
  uint32_t bits = o0 ^ o1;
  float u = __uint_as_float((bits >> 9) | 0x3F800000u) - 1.0f;
  return floorf(u + 0.9f);
}

// bf16 helpers: RNE pack, exact shl unpack
__device__ __forceinline__ uint32_t f2bf(float f) {
  uint32_t u = __float_as_uint(f);
  return (u + 0x7fffu + ((u >> 16) & 1u)) >> 16;
}
__device__ __forceinline__ float bflo(uint32_t u) { return __uint_as_float(u << 16); }
__device__ __forceinline__ float bfhi(uint32_t u) { return __uint_as_float(u & 0xffff0000u); }

// ---------------------------------------------------------------------------
// CSR build (R17): COUNTING SORT with exact precomputed offsets.
// R16 post-mortem: per-bucket global cursor atomics (~1700-2500 same-address
// device-scope RMWs per bucket at ~30-60 ns) were the bin bottleneck — occ
// 19.5->76% changed nothing. R17 removes ALL contended cursors:
//   hist:  per (slice, bucket) LDS counts -> chist[bucket][slice]
//   scanA: bucket totals; scanB: exact offsets boff[bucket][slice]
//          (in-round bucket prefix + slice prefix), bbase/btot per bucket
//   bin:   LDS cursors init'd from boff; barrier-free stream: threefry ->
//          LDS atomicInc -> stage[pos]. No global atomics, no caps/sentinels.
//   ls:    per bucket, exact stage region -> LDS row hist/scan -> rp + rec.
// Full-line invariant preserved: a block's writes to each ~210 B bucket
// range happen within its lifetime (boundary lines ~5 MB extra writeback).
// Plain loads in build (rows hist->L3->bin re-hit; avoid NT L3-bypass trap).
// ---------------------------------------------------------------------------

// hist: 2*SLICES blocks; k<SLICES -> round 0 slice k, else round 1 slice k-SLICES.
__global__ __launch_bounds__(1024) void hist_kernel(
    const int* __restrict__ adj_r, const int* __restrict__ tag_r,
    const int* __restrict__ soc_r, int* __restrict__ chist,
    int nAdj, int nTag, int nSoc) {
  __shared__ int cnt[NBKT1];
  int tid = threadIdx.x, k = blockIdx.x;
  int r = (k >= SLICES) ? 1 : 0;
  int kk = k - r * SLICES;
  int nTot = r ? (nTag + nSoc) : nAdj;
  int nBkt = r ? NBKT1 : NBKT0;
  int bktBase = r ? NBKT0 : 0;
  for (int b = tid; b < nBkt; b += 1024) cnt[b] = 0;
  __syncthreads();
  int per = (nTot + SLICES - 1) / SLICES;
  int e0 = kk * per;
  int e1 = e0 + per; if (e1 > nTot) e1 = nTot;
  for (int e = e0 + tid; e < e1; e += 1024) {
    int j;
    if (r == 0) j = adj_r[e];
    else if (e < nTag) j = tag_r[e];
    else j = MM + soc_r[e - nTag];
    atomicAdd(&cnt[j >> BSH], 1);
  }
  __syncthreads();
  for (int b = tid; b < nBkt; b += 1024)
    chist[(bktBase + b) * SLICES + kk] = cnt[b];
}

// scanA: one block per bucket -> btot[gb] = sum over slices.
__global__ __launch_bounds__(512) void scanA_kernel(const int* __restrict__ chist,
                                                    int* __restrict__ btot) {
  __shared__ int red[512];
  int gb = blockIdx.x, t = threadIdx.x;
  red[t] = chist[gb * SLICES + t];
  __syncthreads();
  for (int off = 256; off > 0; off >>= 1) {
    if (t < off) red[t] += red[t + off];
    __syncthreads();
  }
  if (t == 0) btot[gb] = red[0];
}

// scanB: one block per bucket -> boff[gb][slice] = in-round bucket prefix +
// exclusive slice prefix; bbase[gb] = in-round bucket prefix.
__global__ __launch_bounds__(512) void scanB_kernel(const int* __restrict__ chist,
                                                    const int* __restrict__ btot,
                                                    int* __restrict__ boff,
                                                    int* __restrict__ bbase,
                                                    int* __restrict__ rp, int totE) {
  __shared__ int red[512];
  int gb = blockIdx.x, t = threadIdx.x;
  int rstart = (gb >= NBKT0) ? NBKT0 : 0;
  int ps = 0;
  for (int b = rstart + t; b < gb; b += 512) ps += btot[b];
  red[t] = ps;
  __syncthreads();
  for (int off = 256; off > 0; off >>= 1) {
    if (t < off) red[t] += red[t + off];
    __syncthreads();
  }
  int pb = red[0];
  __syncthreads();
  int c = chist[gb * SLICES + t];
  red[t] = c;
  __syncthreads();
  for (int off = 1; off < 512; off <<= 1) {
    int v = (t >= off) ? red[t - off] : 0;
    __syncthreads();
    red[t] += v;
    __syncthreads();
  }
  boff[gb * SLICES + t] = pb + red[t] - c;
  if (t == 0) {
    bbase[gb] = pb;
    if (gb == 0) rp[NT_ROWS] = totE;
  }
}

// bin: barrier-free scatter to exact offsets. Round-local edge index:
// primary (adj | tag) for e < nPrim, secondary (soc) after, rows +rowOff2.
__global__ __launch_bounds__(1024) void bin_kernel(
    const int* __restrict__ pr, const int* __restrict__ pc, const float* __restrict__ pv,
    const int* __restrict__ sr, const int* __restrict__ scc, const float* __restrict__ sv,
    const int* __restrict__ boff, int2* __restrict__ stage,
    int nPrim, int nTot, int rowOff2, int bktBase, int nBkt,
    uint32_t pa0, uint32_t pa1, uint32_t pb0, uint32_t pb1,
    uint32_t sa0, uint32_t sa1, uint32_t sb0, uint32_t sb1) {
  __shared__ int cur[NBKT1];
  int tid = threadIdx.x, k = blockIdx.x;
  for (int b = tid; b < nBkt; b += 1024) cur[b] = boff[(bktBase + b) * SLICES + k];
  __syncthreads();
  int per = (nTot + SLICES - 1) / SLICES;
  int e0 = k * per;
  int e1 = e0 + per; if (e1 > nTot) e1 = nTot;
  const float SC = (float)(1.0 / 0.9);
  for (int e = e0 + tid; e < e1; e += 1024) {
    int j, c; float v; uint32_t le, k00, k01, k10, k11;
    if (e < nPrim) {
      le = (uint32_t)e;
      j = pr[e]; c = pc[e]; v = pv[e];
      k00 = pa0; k01 = pa1; k10 = pb0; k11 = pb1;
    } else {
      le = (uint32_t)(e - nPrim);
      j = rowOff2 + sr[e - nPrim]; c = scc[e - nPrim]; v = sv[e - nPrim];
      k00 = sa0; k01 = sa1; k10 = sb0; k11 = sb1;
    }
    uint32_t w = f2bf(v * drop_mask(le, k00, k01) * SC) |
                 (f2bf(v * drop_mask(le, k10, k11) * SC) << 16);
    int lb = j >> BSH;
    int pos = atomicAdd(&cur[lb], 1);
    stage[pos] = make_int2(c | ((j & (BROWS - 1)) << 18), (int)w);
  }
}

// Local sort: one block per bucket; exact stage region [bbase, bbase+btot).
// Pass 1: LDS row histogram + scan -> rp. Pass 2: place records into rec.
__global__ __launch_bounds__(512) void ls_kernel(
    int* __restrict__ rp, const int* __restrict__ bbase, const int* __restrict__ btot,
    const int2* __restrict__ stage, int2* __restrict__ rec,
    int rowStart, int rowEnd, int eBase, int bktBase) {
  __shared__ int cur[BROWS];
  __shared__ int red[512];
  int tid = threadIdx.x, lb = blockIdx.x, gb = bktBase + lb;
  int sbase = bbase[gb];
  int nst = btot[gb];
  int base = eBase + sbase;
  cur[tid] = 0; cur[tid + 512] = 0;
  __syncthreads();
  for (int i = tid; i < nst; i += 512)
    atomicAdd(&cur[((uint32_t)stage[sbase + i].x) >> 18], 1);
  __syncthreads();
  int c0 = cur[2 * tid], c1 = cur[2 * tid + 1];
  int pairs = c0 + c1;
  red[tid] = pairs;
  __syncthreads();
  for (int off = 1; off < 512; off <<= 1) {
    int v = (tid >= off) ? red[tid - off] : 0;
    __syncthreads();
    red[tid] += v;
    __syncthreads();
  }
  int excl = red[tid] - pairs;
  int r = rowStart + (lb << BSH) + 2 * tid;
  int p0 = base + excl, p1 = p0 + c0;
  if (r < rowEnd) rp[r] = p0;
  if (r + 1 < rowEnd) rp[r + 1] = p1;
  __syncthreads();
  cur[2 * tid] = p0; cur[2 * tid + 1] = p1;
  __syncthreads();
  for (int i = tid; i < nst; i += 512) {
    int2 m = stage[sbase + i];
    int pos = atomicAdd(&cur[((uint32_t)m.x) >> 18], 1);
    rec[pos] = make_int2((m.x & 0x3FFFF) * DD, m.y);
  }
}

// ---------------------------------------------------------------------------
// Gather SpMM core, BATCHED BRANCH-FREE subgroup-per-row (R11): per 8-edge
// batch, load 8 recs, then issue all 8 feature loads with no intervening
// branches (dropped edges contribute exact 0*x), accumulate into 2
// interleaved accumulator sets. ~8 feature loads in flight per subgroup.
// ---------------------------------------------------------------------------
#define FMA8(c0, c1, v, q) { \
    c0.x += v * bflo(q.x); c0.y += v * bfhi(q.x); \
    c0.z += v * bflo(q.y); c0.w += v * bfhi(q.y); \
    c1.x += v * bflo(q.z); c1.y += v * bfhi(q.z); \
    c1.z += v * bflo(q.w); c1.w += v * bfhi(q.w); }

template <int VS>
__device__ __forceinline__ void gather_sub(int s0, int s1, const int2* __restrict__ rec,
                                           const ushort* __restrict__ src,
                                           int fl, float4& A0, float4& A1) {
  float4 a0 = make_float4(0.f, 0.f, 0.f, 0.f);
  float4 a1 = make_float4(0.f, 0.f, 0.f, 0.f);
  float4 b0 = make_float4(0.f, 0.f, 0.f, 0.f);
  float4 b1 = make_float4(0.f, 0.f, 0.f, 0.f);
  const ushort* sl = src + fl * 8;   // this lane's 16 B slice base
  int i = s0;
  for (; i + 8 <= s1; i += 8) {
    long long r[8];
    uint4 q[8];
#pragma unroll
    for (int u = 0; u < 8; ++u)
      r[u] = __builtin_nontemporal_load((const long long*)(rec + i + u));
#pragma unroll
    for (int u = 0; u < 8; ++u)
      q[u] = *(const uint4*)(sl + (uint32_t)r[u]);
#pragma unroll
    for (int u = 0; u < 8; ++u) {
      uint32_t w = (uint32_t)((unsigned long long)r[u] >> 32);
      float v = VS ? bfhi(w) : bflo(w);
      if (u & 1) { FMA8(b0, b1, v, q[u]) } else { FMA8(a0, a1, v, q[u]) }
    }
  }
  if (i + 4 <= s1) {
    long long r[4];
    uint4 q[4];
#pragma unroll
    for (int u = 0; u < 4; ++u)
      r[u] = __builtin_nontemporal_load((const long long*)(rec + i + u));
#pragma unroll
    for (int u = 0; u < 4; ++u)
      q[u] = *(const uint4*)(sl + (uint32_t)r[u]);
#pragma unroll
    for (int u = 0; u < 4; ++u) {
      uint32_t w = (uint32_t)((unsigned long long)r[u] >> 32);
      float v = VS ? bfhi(w) : bflo(w);
      if (u & 1) { FMA8(b0, b1, v, q[u]) } else { FMA8(a0, a1, v, q[u]) }
    }
    i += 4;
  }
  for (; i < s1; ++i) {
    long long rr = __builtin_nontemporal_load((const long long*)(rec + i));
    uint4 q = *(const uint4*)(sl + (uint32_t)rr);
    uint32_t w = (uint32_t)((unsigned long long)rr >> 32);
    float v = VS ? bfhi(w) : bflo(w);
    FMA8(a0, a1, v, q)
  }
  A0 = make_float4(a0.x + b0.x, a0.y + b0.y, a0.z + b0.z, a0.w + b0.w);
  A1 = make_float4(a1.x + b1.x, a1.y + b1.y, a1.z + b1.z, a1.w + b1.w);
}

__device__ __forceinline__ float4 lk4(float4 x) {
  x.x = x.x >= 0.0f ? x.x : 0.5f * x.x;
  x.y = x.y >= 0.0f ? x.y : 0.5f * x.y;
  x.z = x.z >= 0.0f ? x.z : 0.5f * x.z;
  x.w = x.w >= 0.0f ? x.w : 0.5f * x.w;
  return x;
}

__device__ __forceinline__ uint4 pack8(float4 a, float4 b) {
  uint4 p;
  p.x = f2bf(a.x) | (f2bf(a.y) << 16);
  p.y = f2bf(a.z) | (f2bf(a.w) << 16);
  p.z = f2bf(b.x) | (f2bf(b.y) << 16);
  p.w = f2bf(b.z) | (f2bf(b.w) << 16);
  return p;
}

// Mega gather; grid covers NN rows (+TAG_N virtual rows when WITHTAG).
// r < NN:  o = leaky(adj) + (r<USER ? leaky(soc) : leaky(tag item row))
//   FINAL=false: latOut(bf16) = o ; FINAL=true: acc(f32) += f32(lat[r]) + o
// r >= NN (WITHTAG only): rr = r-NN; tgOut[rr] = leaky(tag row ITEM_N+rr)
// Tag source region = lat + USER_N*DD is CONTIGUOUS [items][tags] by layout.
template <int VS, bool FINAL, bool WITHTAG>
__global__ void gather_mega_kernel(
    const int* __restrict__ arp, const int2* __restrict__ arec,
    const int* __restrict__ srp, const int2* __restrict__ srec,
    const int* __restrict__ trp, const int2* __restrict__ trec,
    const ushort* __restrict__ lat,   // NN x 64 bf16 (tag rows follow it)
    ushort* __restrict__ latOut, ushort* __restrict__ tgOut,
    float* __restrict__ acc) {
  int r = (blockIdx.x * blockDim.x + threadIdx.x) >> 3;
  int fl = threadIdx.x & 7;
  if (WITHTAG && r >= NN) {
    int rr = r - NN;
    if (rr >= TAG_N) return;
    int tr = rr + ITEM_N;
    float4 a0, a1;
    gather_sub<VS>(trp[tr], trp[tr + 1], trec, lat + (size_t)USER_N * DD, fl, a0, a1);
    ((uint4*)(tgOut + (size_t)rr * DD))[fl] = pack8(lk4(a0), lk4(a1));
    return;
  }
  if (r >= NN) return;
  float4 t0, t1, b0, b1;
  gather_sub<VS>(arp[r], arp[r + 1], arec, lat, fl, t0, t1);
  if (r < USER_N) {
    gather_sub<VS>(srp[r], srp[r + 1], srec, lat, fl, b0, b1);
  } else {
    int tr = r - USER_N;
    gather_sub<VS>(trp[tr], trp[tr + 1], trec, lat + (size_t)USER_N * DD, fl, b0, b1);
  }
  t0 = lk4(t0); t1 = lk4(t1); b0 = lk4(b0); b1 = lk4(b1);
  float4 o0 = make_float4(t0.x + b0.x, t0.y + b0.y, t0.z + b0.z, t0.w + b0.w);
  float4 o1 = make_float4(t1.x + b1.x, t1.y + b1.y, t1.z + b1.z, t1.w + b1.w);
  if (FINAL) {
    uint4 l = ((const uint4*)(lat + (size_t)r * DD))[fl];
    float4* ap = (float4*)(acc + (size_t)r * DD);
    float4 v0 = ap[fl * 2], v1 = ap[fl * 2 + 1];
    v0.x += bflo(l.x) + o0.x; v0.y += bfhi(l.x) + o0.y;
    v0.z += bflo(l.y) + o0.z; v0.w += bfhi(l.y) + o0.w;
    v1.x += bflo(l.z) + o1.x; v1.y += bfhi(l.z) + o1.y;
    v1.z += bflo(l.w) + o1.z; v1.w += bfhi(l.w) + o1.w;
    ap[fl * 2] = v0; ap[fl * 2 + 1] = v1;
  } else {
    ((uint4*)(latOut + (size_t)r * DD))[fl] = pack8(o0, o1);
  }
}

// acc(f32) = lat0 = concat(u, i); lat0bf = bf16(lat0); tEmbf = bf16(tEmbeds)
__global__ void init_kernel(const float4* __restrict__ u, const float4* __restrict__ it,
                            const float4* __restrict__ tE,
                            float4* __restrict__ acc, ushort4* __restrict__ lat0bf,
                            ushort4* __restrict__ tEmbf) {
  int idx = blockIdx.x * blockDim.x + threadIdx.x;  // NN*16 + TAG_N*16 float4s
  const int uN = USER_N * 16, nN = NN * 16;
  if (idx < nN) {
    float4 v = (idx < uN) ? u[idx] : it[idx - uN];
    acc[idx] = v;
    ushort4 h;
    h.x = (ushort)f2bf(v.x); h.y = (ushort)f2bf(v.y);
    h.z = (ushort)f2bf(v.z); h.w = (ushort)f2bf(v.w);
    lat0bf[idx] = h;
  } else if (idx < nN + TAG_N * 16) {
    int j = idx - nN;
    float4 v = tE[j];
    ushort4 h;
    h.x = (ushort)f2bf(v.x); h.y = (ushort)f2bf(v.y);
    h.z = (ushort)f2bf(v.z); h.w = (ushort)f2bf(v.w);
    tEmbf[j] = h;
  }
}

extern "C" void kernel_launch(void* const* d_in, const int* in_sizes, int n_in,
                              void* d_out, int out_size, void* d_ws, size_t ws_size,
                              hipStream_t stream) {
  const float* uE    = (const float*)d_in[0];
  const float* iE    = (const float*)d_in[1];
  const float* tEm   = (const float*)d_in[2];
  const int*   adj_r = (const int*)d_in[3];
  const int*   adj_c = (const int*)d_in[4];
  const float* adj_v = (const float*)d_in[5];
  const int*   tag_r = (const int*)d_in[6];
  const int*   tag_c = (const int*)d_in[7];
  const float* tag_v = (const float*)d_in[8];
  const int*   soc_r = (const int*)d_in[9];
  const int*   soc_c = (const int*)d_in[10];
  const float* soc_v = (const float*)d_in[11];
  const int nAdj = in_sizes[5], nTag = in_sizes[8], nSoc = in_sizes[11];
  const int totE = nAdj + nTag + nSoc;

  float* acc = (float*)d_out;

  // Workspace (~78 MB). bf16 regions: [lat0 items][tEmbf] and [lat1][tg1bf]
  // contiguous (tag-gather single-base requirement). Build-phase alias:
  // stage -> lat1bf region (2.72M recs >= max round size; dead until mega0).
  ushort* lat0bf = (ushort*)d_ws;                  // NN*DD bf16
  ushort* tEmbf  = lat0bf + (size_t)NN * DD;       // TAG_N*DD (follows lat0!)
  ushort* lat1bf = tEmbf  + (size_t)TAG_N * DD;    // NN*DD
  ushort* tg1bf  = lat1bf + (size_t)NN * DD;       // TAG_N*DD (follows lat1!)
  int2* stage    = (int2*)lat1bf;                  // alias (dead until mega0)
  int2* rec  = (int2*)(tg1bf + (size_t)TAG_N * DD);   // totE {col*DD, pk}
  int*  ip   = (int*)(rec + totE);
  int* chist = ip;  ip += NBKT * SLICES;           // per (bucket, slice) counts
  int* boff  = ip;  ip += NBKT * SLICES;           // per (bucket, slice) offsets
  int* btot  = ip;  ip += NBKT;
  int* bbase = ip;  ip += NBKT;
  int* rp    = ip;  ip += NT_ROWS + 1;

  // fold_in(key(42), j) for j=0..5 (host-side, deterministic)
  uint32_t kk[6][2];
  for (uint32_t j = 0; j < 6; ++j) tf2x32(0u, 42u, 0u, j, &kk[j][0], &kk[j][1]);

  const int thr = 256;
#define CDIV(a, b) (((a) + (b) - 1) / (b))

  // ---- CSR build: hist, scanA, scanB, bin0, ls0, bin1, ls1 ----
  hist_kernel<<<2 * SLICES, 1024, 0, stream>>>(adj_r, tag_r, soc_r, chist,
                                               nAdj, nTag, nSoc);
  scanA_kernel<<<NBKT, 512, 0, stream>>>(chist, btot);
  scanB_kernel<<<NBKT, 512, 0, stream>>>(chist, btot, boff, bbase, rp, totE);
  // round 0: adj -> local rows [0, NN)
  bin_kernel<<<SLICES, 1024, 0, stream>>>(
      adj_r, adj_c, adj_v, adj_r, adj_c, adj_v,   // secondary unused
      boff, stage, nAdj, nAdj, 0, 0, NBKT0,
      kk[0][0], kk[0][1], kk[3][0], kk[3][1], 0u, 0u, 0u, 0u);
  ls_kernel<<<NBKT0, 512, 0, stream>>>(rp, bbase, btot, stage, rec, 0, NN, 0, 0);
  // round 1: tag (local rows [0,MM)) + soc (local rows [MM, MM+USER_N))
  bin_kernel<<<SLICES, 1024, 0, stream>>>(
      tag_r, tag_c, tag_v, soc_r, soc_c, soc_v,
      boff, stage, nTag, nTag + nSoc, MM, NBKT0, NBKT1,
      kk[1][0], kk[1][1], kk[4][0], kk[4][1],
      kk[2][0], kk[2][1], kk[5][0], kk[5][1]);
  ls_kernel<<<NBKT1, 512, 0, stream>>>(rp, bbase, btot, stage, rec, NN, NT_ROWS, nAdj, NBKT0);

  // ---- init: acc = lat0 (f32); lat0bf, tEmbf (bf16 gather sources) ----
  init_kernel<<<CDIV((NN + TAG_N) * 16, thr), thr, 0, stream>>>(
      (const float4*)uE, (const float4*)iE, (const float4*)tEm,
      (float4*)acc, (ushort4*)lat0bf, (ushort4*)tEmbf);

  // ---- layer 0 (tag-node rows fused into the same launch) ----
  const int* arp = rp;
  const int* trp = rp + NN;
  const int* srp = rp + NN + MM;
  gather_mega_kernel<0, false, true><<<CDIV((NN + TAG_N) * 8, thr), thr, 0, stream>>>(
      arp, rec, srp, rec, trp, rec, lat0bf, lat1bf, tg1bf, nullptr);

  // ---- layer 1 ----
  gather_mega_kernel<1, true, false><<<CDIV(NN * 8, thr), thr, 0, stream>>>(
      arp, rec, srp, rec, trp, rec, lat1bf, nullptr, nullptr, acc);
#undef CDIV
}

// Round 10
// 415.463 us; speedup vs baseline: 1.4627x; 1.0089x over previous
//
#include <hip/hip_runtime.h>
#include <stdint.h>

// Problem constants (match reference)
#define USER_N 100000
#define ITEM_N 50000
#define TAG_N  20000
#define NN (USER_N + ITEM_N)   // 150000 interaction-graph nodes
#define MM (ITEM_N + TAG_N)    // 70000 tag-graph nodes
#define DD 64
#define NT_ROWS (NN + MM + USER_N)   // 320000 merged rows (adj | tag | soc)

// Counting-sort geometry (R17/R18)
#define BSH 10
#define BROWS (1 << BSH)       // 1024 rows per bucket
#define NBKT0 147              // ceil(NN/1024)           — round 0 (adj)
#define NBKT1 167              // ceil((MM+USER_N)/1024)  — round 1 (tag+soc)
#define NBKT (NBKT0 + NBKT1)   // 314
#define SLICES 512             // edge slices (bin/hist blocks) per round
#define NCH 10                 // column chunks (col>>14: 16384 cols = 2 MB window)
#define CSH2 14

// ---------------------------------------------------------------------------
// JAX threefry2x32 (20 rounds), bit-exact (verified: R1 absmax 0.0).
// ---------------------------------------------------------------------------
__host__ __device__ __forceinline__ void tf2x32(uint32_t k0, uint32_t k1,
                                                uint32_t x0, uint32_t x1,
                                                uint32_t* o0, uint32_t* o1) {
  uint32_t ks2 = k0 ^ k1 ^ 0x1BD11BDAu;
#define ROTL32(v, d) (((v) << (d)) | ((v) >> (32 - (d))))
#define TF_RND(d) { x0 += x1; x1 = ROTL32(x1, d); x1 ^= x0; }
  x0 += k0; x1 += k1;
  TF_RND(13) TF_RND(15) TF_RND(26) TF_RND(6)
  x0 += k1;  x1 += ks2 + 1u;
  TF_RND(17) TF_RND(29) TF_RND(16) TF_RND(24)
  x0 += ks2; x1 += k0 + 2u;
  TF_RND(13) TF_RND(15) TF_RND(26) TF_RND(6)
  x0 += k0;  x1 += k1 + 3u;
  TF_RND(17) TF_RND(29) TF_RND(16) TF_RND(24)
  x0 += k1;  x1 += ks2 + 4u;
  TF_RND(13) TF_RND(15) TF_RND(26) TF_RND(6)
  x0 += ks2; x1 += k0 + 5u;
  *o0 = x0; *o1 = x1;
#undef TF_RND
#undef ROTL32
}

// keep-mask(e; key), bit-exact vs jax uniform+floor (e = LOCAL per-graph idx)
__device__ __forceinline__ float drop_mask(uint32_t e, uint32_t k0, uint32_t k1) {
  uint32_t o0, o1;
  tf2x32(k0, k1, 0u, e, &o0, &o1);
  uint32_t bits = o0 ^ o1;
  float u = __uint_as_float((bits >> 9) | 0x3F800000u) - 1.0f;
  return floorf(u + 0.9f);
}

// bf16 helpers: RNE pack, exact shl unpack
__device__ __forceinline__ uint32_t f2bf(float f) {
  uint32_t u = __float_as_uint(f);
  return (u + 0x7fffu + ((u >> 16) & 1u)) >> 16;
}
__device__ __forceinline__ float bflo(uint32_t u) { return __uint_as_float(u << 16); }
__device__ __forceinline__ float bfhi(uint32_t u) { return __uint_as_float(u & 0xffff0000u); }

// ---------------------------------------------------------------------------
// CSR build (R18 = R17 counting sort + COLUMN-CHUNKED record order).
// R17 post-mortem: megas dominate (91 us each) with FETCH 260 MB — random
// columns over the 19.2 MB feature table give ~21% L2 hit (4 MB/XCD) and L3
// doesn't recover the rest. R18: ls places each row's records sorted by
// column CHUNK (col>>14, 2 MB windows). Co-resident waves process record j
// of their rows in near-lockstep, and record j sits at column-quantile
// j/deg -> the machine's live column window at any instant is ~2 MB ->
// L2-resident. rp and the gather kernels are UNCHANGED (order within a row
// is invisible to correctness; fp32 accumulation order shifts only).
// Also: init fused into the hist dispatch (disjoint block ranges).
// ---------------------------------------------------------------------------

// histinit: blocks [0, 2*SLICES) histogram bucket counts (k<SLICES: round 0,
// else round 1). Blocks >= 2*SLICES: init (acc=lat0 f32; lat0bf; tEmbf).
__global__ __launch_bounds__(1024) void histinit_kernel(
    const int* __restrict__ adj_r, const int* __restrict__ tag_r,
    const int* __restrict__ soc_r, int* __restrict__ chist,
    int nAdj, int nTag, int nSoc,
    const float4* __restrict__ u, const float4* __restrict__ it,
    const float4* __restrict__ tE, float4* __restrict__ acc,
    ushort4* __restrict__ lat0bf, ushort4* __restrict__ tEmbf) {
  __shared__ int cnt[NBKT1];
  int tid = threadIdx.x, k = blockIdx.x;
  if (k >= 2 * SLICES) {
    int idx = (k - 2 * SLICES) * 1024 + tid;
    const int uN = USER_N * 16, nN = NN * 16;
    if (idx < nN) {
      float4 v = (idx < uN) ? u[idx] : it[idx - uN];
      acc[idx] = v;
      ushort4 h;
      h.x = (ushort)f2bf(v.x); h.y = (ushort)f2bf(v.y);
      h.z = (ushort)f2bf(v.z); h.w = (ushort)f2bf(v.w);
      lat0bf[idx] = h;
    } else if (idx < nN + TAG_N * 16) {
      int j = idx - nN;
      float4 v = tE[j];
      ushort4 h;
      h.x = (ushort)f2bf(v.x); h.y = (ushort)f2bf(v.y);
      h.z = (ushort)f2bf(v.z); h.w = (ushort)f2bf(v.w);
      tEmbf[j] = h;
    }
    return;
  }
  int r = (k >= SLICES) ? 1 : 0;
  int kk = k - r * SLICES;
  int nTot = r ? (nTag + nSoc) : nAdj;
  int nBkt = r ? NBKT1 : NBKT0;
  int bktBase = r ? NBKT0 : 0;
  for (int b = tid; b < nBkt; b += 1024) cnt[b] = 0;
  __syncthreads();
  int per = (nTot + SLICES - 1) / SLICES;
  int e0 = kk * per;
  int e1 = e0 + per; if (e1 > nTot) e1 = nTot;
  for (int e = e0 + tid; e < e1; e += 1024) {
    int j;
    if (r == 0) j = adj_r[e];
    else if (e < nTag) j = tag_r[e];
    else j = MM + soc_r[e - nTag];
    atomicAdd(&cnt[j >> BSH], 1);
  }
  __syncthreads();
  for (int b = tid; b < nBkt; b += 1024)
    chist[(bktBase + b) * SLICES + kk] = cnt[b];
}

// scanA: one block per bucket -> btot[gb] = sum over slices.
__global__ __launch_bounds__(512) void scanA_kernel(const int* __restrict__ chist,
                                                    int* __restrict__ btot) {
  __shared__ int red[512];
  int gb = blockIdx.x, t = threadIdx.x;
  red[t] = chist[gb * SLICES + t];
  __syncthreads();
  for (int off = 256; off > 0; off >>= 1) {
    if (t < off) red[t] += red[t + off];
    __syncthreads();
  }
  if (t == 0) btot[gb] = red[0];
}

// scanB: one block per bucket -> boff[gb][slice] = in-round bucket prefix +
// exclusive slice prefix; bbase[gb] = in-round bucket prefix.
__global__ __launch_bounds__(512) void scanB_kernel(const int* __restrict__ chist,
                                                    const int* __restrict__ btot,
                                                    int* __restrict__ boff,
                                                    int* __restrict__ bbase,
                                                    int* __restrict__ rp, int totE) {
  __shared__ int red[512];
  int gb = blockIdx.x, t = threadIdx.x;
  int rstart = (gb >= NBKT0) ? NBKT0 : 0;
  int ps = 0;
  for (int b = rstart + t; b < gb; b += 512) ps += btot[b];
  red[t] = ps;
  __syncthreads();
  for (int off = 256; off > 0; off >>= 1) {
    if (t < off) red[t] += red[t + off];
    __syncthreads();
  }
  int pb = red[0];
  __syncthreads();
  int c = chist[gb * SLICES + t];
  red[t] = c;
  __syncthreads();
  for (int off = 1; off < 512; off <<= 1) {
    int v = (t >= off) ? red[t - off] : 0;
    __syncthreads();
    red[t] += v;
    __syncthreads();
  }
  boff[gb * SLICES + t] = pb + red[t] - c;
  if (t == 0) {
    bbase[gb] = pb;
    if (gb == 0) rp[NT_ROWS] = totE;
  }
}

// bin: barrier-free scatter to exact offsets. Round-local edge index:
// primary (adj | tag) for e < nPrim, secondary (soc) after, rows +rowOff2.
__global__ __launch_bounds__(1024) void bin_kernel(
    const int* __restrict__ pr, const int* __restrict__ pc, const float* __restrict__ pv,
    const int* __restrict__ sr, const int* __restrict__ scc, const float* __restrict__ sv,
    const int* __restrict__ boff, int2* __restrict__ stage,
    int nPrim, int nTot, int rowOff2, int bktBase, int nBkt,
    uint32_t pa0, uint32_t pa1, uint32_t pb0, uint32_t pb1,
    uint32_t sa0, uint32_t sa1, uint32_t sb0, uint32_t sb1) {
  __shared__ int cur[NBKT1];
  int tid = threadIdx.x, k = blockIdx.x;
  for (int b = tid; b < nBkt; b += 1024) cur[b] = boff[(bktBase + b) * SLICES + k];
  __syncthreads();
  int per = (nTot + SLICES - 1) / SLICES;
  int e0 = k * per;
  int e1 = e0 + per; if (e1 > nTot) e1 = nTot;
  const float SC = (float)(1.0 / 0.9);
  for (int e = e0 + tid; e < e1; e += 1024) {
    int j, c; float v; uint32_t le, k00, k01, k10, k11;
    if (e < nPrim) {
      le = (uint32_t)e;
      j = pr[e]; c = pc[e]; v = pv[e];
      k00 = pa0; k01 = pa1; k10 = pb0; k11 = pb1;
    } else {
      le = (uint32_t)(e - nPrim);
      j = rowOff2 + sr[e - nPrim]; c = scc[e - nPrim]; v = sv[e - nPrim];
      k00 = sa0; k01 = sa1; k10 = sb0; k11 = sb1;
    }
    uint32_t w = f2bf(v * drop_mask(le, k00, k01) * SC) |
                 (f2bf(v * drop_mask(le, k10, k11) * SC) << 16);
    int lb = j >> BSH;
    int pos = atomicAdd(&cur[lb], 1);
    stage[pos] = make_int2(c | ((j & (BROWS - 1)) << 18), (int)w);
  }
}

// Local sort (R18): one block per bucket; exact stage region. LDS cursors
// per (row, column-chunk) -> records within each row come out sorted by
// column chunk. Pass 1: (row,chunk) histogram. Scan 10240 entries (20 per
// thread + block scan). rp[r] = prefix at (r, chunk 0). Pass 2: place.
__global__ __launch_bounds__(512) void ls_kernel(
    int* __restrict__ rp, const int* __restrict__ bbase, const int* __restrict__ btot,
    const int2* __restrict__ stage, int2* __restrict__ rec,
    int rowStart, int rowEnd, int eBase, int bktBase) {
  __shared__ int cur[BROWS * NCH];   // 40 KB
  __shared__ int red[512];
  int tid = threadIdx.x, lb = blockIdx.x, gb = bktBase + lb;
  int sbase = bbase[gb];
  int nst = btot[gb];
  int base = eBase + sbase;
  for (int i = tid; i < BROWS * NCH; i += 512) cur[i] = 0;
  __syncthreads();
  for (int i = tid; i < nst; i += 512) {
    int mx = stage[sbase + i].x;
    atomicAdd(&cur[(((uint32_t)mx) >> 18) * NCH + ((mx & 0x3FFFF) >> CSH2)], 1);
  }
  __syncthreads();
  const int PT = (BROWS * NCH) / 512;   // 20 entries per thread
  int loc[PT];
  int s = 0;
  int o0 = tid * PT;
#pragma unroll
  for (int u = 0; u < PT; ++u) { loc[u] = s; s += cur[o0 + u]; }
  red[tid] = s;
  __syncthreads();
  for (int off = 1; off < 512; off <<= 1) {
    int v = (tid >= off) ? red[tid - off] : 0;
    __syncthreads();
    red[tid] += v;
    __syncthreads();
  }
  int excl = red[tid] - s;
#pragma unroll
  for (int u = 0; u < PT; ++u) {
    int idx = o0 + u;
    int p = base + excl + loc[u];
    cur[idx] = p;
    if ((idx % NCH) == 0) {
      int r = rowStart + (lb << BSH) + idx / NCH;
      if (r < rowEnd) rp[r] = p;
    }
  }
  __syncthreads();
  for (int i = tid; i < nst; i += 512) {
    int2 m = stage[sbase + i];
    int col = m.x & 0x3FFFF;
    int pos = atomicAdd(&cur[(((uint32_t)m.x) >> 18) * NCH + (col >> CSH2)], 1);
    rec[pos] = make_int2(col * DD, m.y);
  }
}

// ---------------------------------------------------------------------------
// Gather SpMM core, BATCHED BRANCH-FREE subgroup-per-row (R11): per 8-edge
// batch, load 8 recs, then issue all 8 feature loads with no intervening
// branches (dropped edges contribute exact 0*x), accumulate into 2
// interleaved accumulator sets. ~8 feature loads in flight per subgroup.
// R18: records are column-chunk-sorted -> chunk-local source access.
// ---------------------------------------------------------------------------
#define FMA8(c0, c1, v, q) { \
    c0.x += v * bflo(q.x); c0.y += v * bfhi(q.x); \
    c0.z += v * bflo(q.y); c0.w += v * bfhi(q.y); \
    c1.x += v * bflo(q.z); c1.y += v * bfhi(q.z); \
    c1.z += v * bflo(q.w); c1.w += v * bfhi(q.w); }

template <int VS>
__device__ __forceinline__ void gather_sub(int s0, int s1, const int2* __restrict__ rec,
                                           const ushort* __restrict__ src,
                                           int fl, float4& A0, float4& A1) {
  float4 a0 = make_float4(0.f, 0.f, 0.f, 0.f);
  float4 a1 = make_float4(0.f, 0.f, 0.f, 0.f);
  float4 b0 = make_float4(0.f, 0.f, 0.f, 0.f);
  float4 b1 = make_float4(0.f, 0.f, 0.f, 0.f);
  const ushort* sl = src + fl * 8;   // this lane's 16 B slice base
  int i = s0;
  for (; i + 8 <= s1; i += 8) {
    long long r[8];
    uint4 q[8];
#pragma unroll
    for (int u = 0; u < 8; ++u)
      r[u] = __builtin_nontemporal_load((const long long*)(rec + i + u));
#pragma unroll
    for (int u = 0; u < 8; ++u)
      q[u] = *(const uint4*)(sl + (uint32_t)r[u]);
#pragma unroll
    for (int u = 0; u < 8; ++u) {
      uint32_t w = (uint32_t)((unsigned long long)r[u] >> 32);
      float v = VS ? bfhi(w) : bflo(w);
      if (u & 1) { FMA8(b0, b1, v, q[u]) } else { FMA8(a0, a1, v, q[u]) }
    }
  }
  if (i + 4 <= s1) {
    long long r[4];
    uint4 q[4];
#pragma unroll
    for (int u = 0; u < 4; ++u)
      r[u] = __builtin_nontemporal_load((const long long*)(rec + i + u));
#pragma unroll
    for (int u = 0; u < 4; ++u)
      q[u] = *(const uint4*)(sl + (uint32_t)r[u]);
#pragma unroll
    for (int u = 0; u < 4; ++u) {
      uint32_t w = (uint32_t)((unsigned long long)r[u] >> 32);
      float v = VS ? bfhi(w) : bflo(w);
      if (u & 1) { FMA8(b0, b1, v, q[u]) } else { FMA8(a0, a1, v, q[u]) }
    }
    i += 4;
  }
  for (; i < s1; ++i) {
    long long rr = __builtin_nontemporal_load((const long long*)(rec + i));
    uint4 q = *(const uint4*)(sl + (uint32_t)rr);
    uint32_t w = (uint32_t)((unsigned long long)rr >> 32);
    float v = VS ? bfhi(w) : bflo(w);
    FMA8(a0, a1, v, q)
  }
  A0 = make_float4(a0.x + b0.x, a0.y + b0.y, a0.z + b0.z, a0.w + b0.w);
  A1 = make_float4(a1.x + b1.x, a1.y + b1.y, a1.z + b1.z, a1.w + b1.w);
}

__device__ __forceinline__ float4 lk4(float4 x) {
  x.x = x.x >= 0.0f ? x.x : 0.5f * x.x;
  x.y = x.y >= 0.0f ? x.y : 0.5f * x.y;
  x.z = x.z >= 0.0f ? x.z : 0.5f * x.z;
  x.w = x.w >= 0.0f ? x.w : 0.5f * x.w;
  return x;
}

__device__ __forceinline__ uint4 pack8(float4 a, float4 b) {
  uint4 p;
  p.x = f2bf(a.x) | (f2bf(a.y) << 16);
  p.y = f2bf(a.z) | (f2bf(a.w) << 16);
  p.z = f2bf(b.x) | (f2bf(b.y) << 16);
  p.w = f2bf(b.z) | (f2bf(b.w) << 16);
  return p;
}

// Mega gather; grid covers NN rows (+TAG_N virtual rows when WITHTAG).
// r < NN:  o = leaky(adj) + (r<USER ? leaky(soc) : leaky(tag item row))
//   FINAL=false: latOut(bf16) = o ; FINAL=true: acc(f32) += f32(lat[r]) + o
// r >= NN (WITHTAG only): rr = r-NN; tgOut[rr] = leaky(tag row ITEM_N+rr)
// Tag source region = lat + USER_N*DD is CONTIGUOUS [items][tags] by layout.
template <int VS, bool FINAL, bool WITHTAG>
__global__ void gather_mega_kernel(
    const int* __restrict__ arp, const int2* __restrict__ arec,
    const int* __restrict__ srp, const int2* __restrict__ srec,
    const int* __restrict__ trp, const int2* __restrict__ trec,
    const ushort* __restrict__ lat,   // NN x 64 bf16 (tag rows follow it)
    ushort* __restrict__ latOut, ushort* __restrict__ tgOut,
    float* __restrict__ acc) {
  int r = (blockIdx.x * blockDim.x + threadIdx.x) >> 3;
  int fl = threadIdx.x & 7;
  if (WITHTAG && r >= NN) {
    int rr = r - NN;
    if (rr >= TAG_N) return;
    int tr = rr + ITEM_N;
    float4 a0, a1;
    gather_sub<VS>(trp[tr], trp[tr + 1], trec, lat + (size_t)USER_N * DD, fl, a0, a1);
    ((uint4*)(tgOut + (size_t)rr * DD))[fl] = pack8(lk4(a0), lk4(a1));
    return;
  }
  if (r >= NN) return;
  float4 t0, t1, b0, b1;
  gather_sub<VS>(arp[r], arp[r + 1], arec, lat, fl, t0, t1);
  if (r < USER_N) {
    gather_sub<VS>(srp[r], srp[r + 1], srec, lat, fl, b0, b1);
  } else {
    int tr = r - USER_N;
    gather_sub<VS>(trp[tr], trp[tr + 1], trec, lat + (size_t)USER_N * DD, fl, b0, b1);
  }
  t0 = lk4(t0); t1 = lk4(t1); b0 = lk4(b0); b1 = lk4(b1);
  float4 o0 = make_float4(t0.x + b0.x, t0.y + b0.y, t0.z + b0.z, t0.w + b0.w);
  float4 o1 = make_float4(t1.x + b1.x, t1.y + b1.y, t1.z + b1.z, t1.w + b1.w);
  if (FINAL) {
    uint4 l = ((const uint4*)(lat + (size_t)r * DD))[fl];
    float4* ap = (float4*)(acc + (size_t)r * DD);
    float4 v0 = ap[fl * 2], v1 = ap[fl * 2 + 1];
    v0.x += bflo(l.x) + o0.x; v0.y += bfhi(l.x) + o0.y;
    v0.z += bflo(l.y) + o0.z; v0.w += bfhi(l.y) + o0.w;
    v1.x += bflo(l.z) + o1.x; v1.y += bfhi(l.z) + o1.y;
    v1.z += bflo(l.w) + o1.z; v1.w += bfhi(l.w) + o1.w;
    ap[fl * 2] = v0; ap[fl * 2 + 1] = v1;
  } else {
    ((uint4*)(latOut + (size_t)r * DD))[fl] = pack8(o0, o1);
  }
}

extern "C" void kernel_launch(void* const* d_in, const int* in_sizes, int n_in,
                              void* d_out, int out_size, void* d_ws, size_t ws_size,
                              hipStream_t stream) {
  const float* uE    = (const float*)d_in[0];
  const float* iE    = (const float*)d_in[1];
  const float* tEm   = (const float*)d_in[2];
  const int*   adj_r = (const int*)d_in[3];
  const int*   adj_c = (const int*)d_in[4];
  const float* adj_v = (const float*)d_in[5];
  const int*   tag_r = (const int*)d_in[6];
  const int*   tag_c = (const int*)d_in[7];
  const float* tag_v = (const float*)d_in[8];
  const int*   soc_r = (const int*)d_in[9];
  const int*   soc_c = (const int*)d_in[10];
  const float* soc_v = (const float*)d_in[11];
  const int nAdj = in_sizes[5], nTag = in_sizes[8], nSoc = in_sizes[11];
  const int totE = nAdj + nTag + nSoc;

  float* acc = (float*)d_out;

  // Workspace (~78 MB). bf16 regions: [lat0 items][tEmbf] and [lat1][tg1bf]
  // contiguous (tag-gather single-base requirement). Build-phase alias:
  // stage -> lat1bf region (2.72M recs >= max round size; dead until mega0).
  ushort* lat0bf = (ushort*)d_ws;                  // NN*DD bf16
  ushort* tEmbf  = lat0bf + (size_t)NN * DD;       // TAG_N*DD (follows lat0!)
  ushort* lat1bf = tEmbf  + (size_t)TAG_N * DD;    // NN*DD
  ushort* tg1bf  = lat1bf + (size_t)NN * DD;       // TAG_N*DD (follows lat1!)
  int2* stage    = (int2*)lat1bf;                  // alias (dead until mega0)
  int2* rec  = (int2*)(tg1bf + (size_t)TAG_N * DD);   // totE {col*DD, pk}
  int*  ip   = (int*)(rec + totE);
  int* chist = ip;  ip += NBKT * SLICES;           // per (bucket, slice) counts
  int* boff  = ip;  ip += NBKT * SLICES;           // per (bucket, slice) offsets
  int* btot  = ip;  ip += NBKT;
  int* bbase = ip;  ip += NBKT;
  int* rp    = ip;  ip += NT_ROWS + 1;

  // fold_in(key(42), j) for j=0..5 (host-side, deterministic)
  uint32_t kk[6][2];
  for (uint32_t j = 0; j < 6; ++j) tf2x32(0u, 42u, 0u, j, &kk[j][0], &kk[j][1]);

  const int thr = 256;
#define CDIV(a, b) (((a) + (b) - 1) / (b))

  // ---- CSR build: histinit, scanA, scanB, bin0, ls0, bin1, ls1 ----
  int initBlocks = CDIV((NN + TAG_N) * 16, 1024);
  histinit_kernel<<<2 * SLICES + initBlocks, 1024, 0, stream>>>(
      adj_r, tag_r, soc_r, chist, nAdj, nTag, nSoc,
      (const float4*)uE, (const float4*)iE, (const float4*)tEm,
      (float4*)acc, (ushort4*)lat0bf, (ushort4*)tEmbf);
  scanA_kernel<<<NBKT, 512, 0, stream>>>(chist, btot);
  scanB_kernel<<<NBKT, 512, 0, stream>>>(chist, btot, boff, bbase, rp, totE);
  // round 0: adj -> local rows [0, NN)
  bin_kernel<<<SLICES, 1024, 0, stream>>>(
      adj_r, adj_c, adj_v, adj_r, adj_c, adj_v,   // secondary unused
      boff, stage, nAdj, nAdj, 0, 0, NBKT0,
      kk[0][0], kk[0][1], kk[3][0], kk[3][1], 0u, 0u, 0u, 0u);
  ls_kernel<<<NBKT0, 512, 0, stream>>>(rp, bbase, btot, stage, rec, 0, NN, 0, 0);
  // round 1: tag (local rows [0,MM)) + soc (local rows [MM, MM+USER_N))
  bin_kernel<<<SLICES, 1024, 0, stream>>>(
      tag_r, tag_c, tag_v, soc_r, soc_c, soc_v,
      boff, stage, nTag, nTag + nSoc, MM, NBKT0, NBKT1,
      kk[1][0], kk[1][1], kk[4][0], kk[4][1],
      kk[2][0], kk[2][1], kk[5][0], kk[5][1]);
  ls_kernel<<<NBKT1, 512, 0, stream>>>(rp, bbase, btot, stage, rec, NN, NT_ROWS, nAdj, NBKT0);

  // ---- layer 0 (tag-node rows fused into the same launch) ----
  const int* arp = rp;
  const int* trp = rp + NN;
  const int* srp = rp + NN + MM;
  gather_mega_kernel<0, false, true><<<CDIV((NN + TAG_N) * 8, thr), thr, 0, stream>>>(
      arp, rec, srp, rec, trp, rec, lat0bf, lat1bf, tg1bf, nullptr);

  // ---- layer 1 ----
  gather_mega_kernel<1, true, false><<<CDIV(NN * 8, thr), thr, 0, stream>>>(
      arp, rec, srp, rec, trp, rec, lat1bf, nullptr, nullptr, acc);
#undef CDIV
}

// Round 11
// 383.539 us; speedup vs baseline: 1.5845x; 1.0832x over previous
//
#include <hip/hip_runtime.h>
#include <stdint.h>

// Problem constants (match reference)
#define USER_N 100000
#define ITEM_N 50000
#define TAG_N  20000
#define NN (USER_N + ITEM_N)   // 150000 interaction-graph nodes
#define MM (ITEM_N + TAG_N)    // 70000 tag-graph nodes
#define DD 64
#define NT_ROWS (NN + MM + USER_N)   // 320000 merged rows (adj | tag | soc)

// Counting-sort geometry (R17/R19)
#define BSH 10
#define BROWS (1 << BSH)       // 1024 rows per bucket
#define NBKT0 147              // ceil(NN/1024)           — round 0 (adj)
#define NBKT1 167              // ceil((MM+USER_N)/1024)  — round 1 (tag+soc)
#define NBKT (NBKT0 + NBKT1)   // 314
#define SLICES 512             // edge slices (bin/hist blocks) per round

// ---------------------------------------------------------------------------
// JAX threefry2x32 (20 rounds), bit-exact (verified: R1 absmax 0.0).
// ---------------------------------------------------------------------------
__host__ __device__ __forceinline__ void tf2x32(uint32_t k0, uint32_t k1,
                                                uint32_t x0, uint32_t x1,
                                                uint32_t* o0, uint32_t* o1) {
  uint32_t ks2 = k0 ^ k1 ^ 0x1BD11BDAu;
#define ROTL32(v, d) (((v) << (d)) | ((v) >> (32 - (d))))
#define TF_RND(d) { x0 += x1; x1 = ROTL32(x1, d); x1 ^= x0; }
  x0 += k0; x1 += k1;
  TF_RND(13) TF_RND(15) TF_RND(26) TF_RND(6)
  x0 += k1;  x1 += ks2 + 1u;
  TF_RND(17) TF_RND(29) TF_RND(16) TF_RND(24)
  x0 += ks2; x1 += k0 + 2u;
  TF_RND(13) TF_RND(15) TF_RND(26) TF_RND(6)
  x0 += k0;  x1 += k1 + 3u;
  TF_RND(17) TF_RND(29) TF_RND(16) TF_RND(24)
  x0 += k1;  x1 += ks2 + 4u;
  TF_RND(13) TF_RND(15) TF_RND(26) TF_RND(6)
  x0 += ks2; x1 += k0 + 5u;
  *o0 = x0; *o1 = x1;
#undef TF_RND
#undef ROTL32
}

// keep-mask(e; key), bit-exact vs jax uniform+floor (e = LOCAL per-graph idx)
__device__ __forceinline__ float drop_mask(uint32_t e, uint32_t k0, uint32_t k1) {
  uint32_t o0, o1;
  tf2x32(k0, k1, 0u, e, &o0, &o1);
  uint32_t bits = o0 ^ o1;
  float u = __uint_as_float((bits >> 9) | 0x3F800000u) - 1.0f;
  return floorf(u + 0.9f);
}

// bf16 helpers: RNE pack, exact shl unpack
__device__ __forceinline__ uint32_t f2bf(float f) {
  uint32_t u = __float_as_uint(f);
  return (u + 0x7fffu + ((u >> 16) & 1u)) >> 16;
}
__device__ __forceinline__ float bflo(uint32_t u) { return __uint_as_float(u << 16); }
__device__ __forceinline__ float bfhi(uint32_t u) { return __uint_as_float(u & 0xffff0000u); }

// ---------------------------------------------------------------------------
// CSR build (R19 = R17 counting sort, rounds CONCURRENT):
// R18's per-row column-chunk sort was a null (rows ~13 edges < 10 chunks ->
// no locality created); reverted to per-row cursors. R19 structure changes:
//  - stage1 moved to d_out (acc no longer pre-initialized; mega1 reads
//    uE/iE directly, same f32 precision) -> stage0 (lat1bf alias) and
//    stage1 disjoint -> bin0+bin1 fused (1024 blocks), ls0+ls1 fused (314
//    blocks): 7 dispatches total, rounds overlap on the machine.
// ---------------------------------------------------------------------------

// histinit: blocks [0, 2*SLICES) histogram bucket counts (k<SLICES: round 0,
// else round 1). Blocks >= 2*SLICES: init lat0bf/tEmbf (bf16 sources).
__global__ __launch_bounds__(1024) void histinit_kernel(
    const int* __restrict__ adj_r, const int* __restrict__ tag_r,
    const int* __restrict__ soc_r, int* __restrict__ chist,
    int nAdj, int nTag, int nSoc,
    const float4* __restrict__ u, const float4* __restrict__ it,
    const float4* __restrict__ tE,
    ushort4* __restrict__ lat0bf, ushort4* __restrict__ tEmbf) {
  __shared__ int cnt[NBKT1];
  int tid = threadIdx.x, k = blockIdx.x;
  if (k >= 2 * SLICES) {
    int idx = (k - 2 * SLICES) * 1024 + tid;
    const int uN = USER_N * 16, nN = NN * 16;
    if (idx < nN) {
      float4 v = (idx < uN) ? u[idx] : it[idx - uN];
      ushort4 h;
      h.x = (ushort)f2bf(v.x); h.y = (ushort)f2bf(v.y);
      h.z = (ushort)f2bf(v.z); h.w = (ushort)f2bf(v.w);
      lat0bf[idx] = h;
    } else if (idx < nN + TAG_N * 16) {
      int j = idx - nN;
      float4 v = tE[j];
      ushort4 h;
      h.x = (ushort)f2bf(v.x); h.y = (ushort)f2bf(v.y);
      h.z = (ushort)f2bf(v.z); h.w = (ushort)f2bf(v.w);
      tEmbf[j] = h;
    }
    return;
  }
  int r = (k >= SLICES) ? 1 : 0;
  int kk = k - r * SLICES;
  int nTot = r ? (nTag + nSoc) : nAdj;
  int nBkt = r ? NBKT1 : NBKT0;
  int bktBase = r ? NBKT0 : 0;
  for (int b = tid; b < nBkt; b += 1024) cnt[b] = 0;
  __syncthreads();
  int per = (nTot + SLICES - 1) / SLICES;
  int e0 = kk * per;
  int e1 = e0 + per; if (e1 > nTot) e1 = nTot;
  for (int e = e0 + tid; e < e1; e += 1024) {
    int j;
    if (r == 0) j = adj_r[e];
    else if (e < nTag) j = tag_r[e];
    else j = MM + soc_r[e - nTag];
    atomicAdd(&cnt[j >> BSH], 1);
  }
  __syncthreads();
  for (int b = tid; b < nBkt; b += 1024)
    chist[(bktBase + b) * SLICES + kk] = cnt[b];
}

// scanA: one block per bucket -> btot[gb] = sum over slices.
__global__ __launch_bounds__(512) void scanA_kernel(const int* __restrict__ chist,
                                                    int* __restrict__ btot) {
  __shared__ int red[512];
  int gb = blockIdx.x, t = threadIdx.x;
  red[t] = chist[gb * SLICES + t];
  __syncthreads();
  for (int off = 256; off > 0; off >>= 1) {
    if (t < off) red[t] += red[t + off];
    __syncthreads();
  }
  if (t == 0) btot[gb] = red[0];
}

// scanB: one block per bucket -> boff[gb][slice] = in-round bucket prefix +
// exclusive slice prefix; bbase[gb] = in-round bucket prefix.
__global__ __launch_bounds__(512) void scanB_kernel(const int* __restrict__ chist,
                                                    const int* __restrict__ btot,
                                                    int* __restrict__ boff,
                                                    int* __restrict__ bbase,
                                                    int* __restrict__ rp, int totE) {
  __shared__ int red[512];
  int gb = blockIdx.x, t = threadIdx.x;
  int rstart = (gb >= NBKT0) ? NBKT0 : 0;
  int ps = 0;
  for (int b = rstart + t; b < gb; b += 512) ps += btot[b];
  red[t] = ps;
  __syncthreads();
  for (int off = 256; off > 0; off >>= 1) {
    if (t < off) red[t] += red[t + off];
    __syncthreads();
  }
  int pb = red[0];
  __syncthreads();
  int c = chist[gb * SLICES + t];
  red[t] = c;
  __syncthreads();
  for (int off = 1; off < 512; off <<= 1) {
    int v = (t >= off) ? red[t - off] : 0;
    __syncthreads();
    red[t] += v;
    __syncthreads();
  }
  boff[gb * SLICES + t] = pb + red[t] - c;
  if (t == 0) {
    bbase[gb] = pb;
    if (gb == 0) rp[NT_ROWS] = totE;
  }
}

// bin01: BOTH rounds in one dispatch (k<SLICES: round 0 -> stage0;
// else round 1 -> stage1). Barrier-free scatter to exact offsets.
__global__ __launch_bounds__(1024) void bin01_kernel(
    const int* __restrict__ adj_r, const int* __restrict__ adj_c, const float* __restrict__ adj_v,
    const int* __restrict__ tag_r, const int* __restrict__ tag_c, const float* __restrict__ tag_v,
    const int* __restrict__ soc_r, const int* __restrict__ soc_c, const float* __restrict__ soc_v,
    const int* __restrict__ boff, int2* __restrict__ stage0, int2* __restrict__ stage1,
    int nAdj, int nTag, int nSoc,
    uint32_t a0, uint32_t a1, uint32_t a2, uint32_t a3,
    uint32_t t0, uint32_t t1, uint32_t t2, uint32_t t3,
    uint32_t s0, uint32_t s1, uint32_t s2, uint32_t s3) {
  __shared__ int cur[NBKT1];
  int tid = threadIdx.x, k = blockIdx.x;
  int rnd = (k >= SLICES) ? 1 : 0;
  int kk = k - rnd * SLICES;
  int nTot = rnd ? (nTag + nSoc) : nAdj;
  int nBkt = rnd ? NBKT1 : NBKT0;
  int bktBase = rnd ? NBKT0 : 0;
  int2* stage = rnd ? stage1 : stage0;
  for (int b = tid; b < nBkt; b += 1024) cur[b] = boff[(bktBase + b) * SLICES + kk];
  __syncthreads();
  int per = (nTot + SLICES - 1) / SLICES;
  int e0 = kk * per;
  int e1 = e0 + per; if (e1 > nTot) e1 = nTot;
  const float SC = (float)(1.0 / 0.9);
  for (int e = e0 + tid; e < e1; e += 1024) {
    int j, c; float v; uint32_t le, k00, k01, k10, k11;
    if (rnd == 0) {
      le = (uint32_t)e;
      j = adj_r[e]; c = adj_c[e]; v = adj_v[e];
      k00 = a0; k01 = a1; k10 = a2; k11 = a3;
    } else if (e < nTag) {
      le = (uint32_t)e;
      j = tag_r[e]; c = tag_c[e]; v = tag_v[e];
      k00 = t0; k01 = t1; k10 = t2; k11 = t3;
    } else {
      le = (uint32_t)(e - nTag);
      j = MM + soc_r[e - nTag]; c = soc_c[e - nTag]; v = soc_v[e - nTag];
      k00 = s0; k01 = s1; k10 = s2; k11 = s3;
    }
    uint32_t w = f2bf(v * drop_mask(le, k00, k01) * SC) |
                 (f2bf(v * drop_mask(le, k10, k11) * SC) << 16);
    int lb = j >> BSH;
    int pos = atomicAdd(&cur[lb], 1);
    stage[pos] = make_int2(c | ((j & (BROWS - 1)) << 18), (int)w);
  }
}

// ls01: BOTH rounds in one dispatch; one block per bucket; exact stage
// region. Pass 1: LDS row histogram + scan -> rp. Pass 2: place into rec.
__global__ __launch_bounds__(512) void ls01_kernel(
    int* __restrict__ rp, const int* __restrict__ bbase, const int* __restrict__ btot,
    const int2* __restrict__ stage0, const int2* __restrict__ stage1,
    int2* __restrict__ rec, int nAdj) {
  __shared__ int cur[BROWS];
  __shared__ int red[512];
  int tid = threadIdx.x, gb = blockIdx.x;
  int rnd = (gb >= NBKT0) ? 1 : 0;
  int lb = rnd ? gb - NBKT0 : gb;
  const int2* stage = rnd ? stage1 : stage0;
  int rowStart = rnd ? NN : 0;
  int rowEnd = rnd ? NT_ROWS : NN;
  int eBase = rnd ? nAdj : 0;
  int sbase = bbase[gb];
  int nst = btot[gb];
  int base = eBase + sbase;
  cur[tid] = 0; cur[tid + 512] = 0;
  __syncthreads();
  for (int i = tid; i < nst; i += 512)
    atomicAdd(&cur[((uint32_t)stage[sbase + i].x) >> 18], 1);
  __syncthreads();
  int c0 = cur[2 * tid], c1 = cur[2 * tid + 1];
  int pairs = c0 + c1;
  red[tid] = pairs;
  __syncthreads();
  for (int off = 1; off < 512; off <<= 1) {
    int v = (tid >= off) ? red[tid - off] : 0;
    __syncthreads();
    red[tid] += v;
    __syncthreads();
  }
  int excl = red[tid] - pairs;
  int r = rowStart + (lb << BSH) + 2 * tid;
  int p0 = base + excl, p1 = p0 + c0;
  if (r < rowEnd) rp[r] = p0;
  if (r + 1 < rowEnd) rp[r + 1] = p1;
  __syncthreads();
  cur[2 * tid] = p0; cur[2 * tid + 1] = p1;
  __syncthreads();
  for (int i = tid; i < nst; i += 512) {
    int2 m = stage[sbase + i];
    int pos = atomicAdd(&cur[((uint32_t)m.x) >> 18], 1);
    rec[pos] = make_int2((m.x & 0x3FFFF) * DD, m.y);
  }
}

// ---------------------------------------------------------------------------
// Gather SpMM core (R19): 16-edge chunk, ONE rec-wait + ONE feature-wait
// per chunk. R11/R17 structure had 3 serialized batch groups per row
// (8/4/1), each paying NT-rec HBM latency (~900cy) + feature latency —
// ~6 exposed waits per gather. R19: load 16 recs in one volley (over-read
// past the row end is safe: rec has 16 slack entries, and feature-load
// offsets for u>=n are CLAMPED to 0 — branchless cndmask — so no garbage
// address and no 0*Inf NaN; v is masked to 0 for u>=n).
// ---------------------------------------------------------------------------
#define FMA8(c0, c1, v, q) { \
    c0.x += v * bflo(q.x); c0.y += v * bfhi(q.x); \
    c0.z += v * bflo(q.y); c0.w += v * bfhi(q.y); \
    c1.x += v * bflo(q.z); c1.y += v * bfhi(q.z); \
    c1.z += v * bflo(q.w); c1.w += v * bfhi(q.w); }

template <int VS>
__device__ __forceinline__ void gather_sub(int s0, int s1, const int2* __restrict__ rec,
                                           const ushort* __restrict__ src,
                                           int fl, float4& A0, float4& A1) {
  float4 a0 = make_float4(0.f, 0.f, 0.f, 0.f);
  float4 a1 = make_float4(0.f, 0.f, 0.f, 0.f);
  float4 b0 = make_float4(0.f, 0.f, 0.f, 0.f);
  float4 b1 = make_float4(0.f, 0.f, 0.f, 0.f);
  const ushort* sl = src + fl * 8;   // this lane's 16 B slice base
  for (int i = s0; i < s1; i += 16) {
    int n = s1 - i;                  // records remaining (may exceed 16)
    long long r[16];
#pragma unroll
    for (int u = 0; u < 16; ++u)
      r[u] = __builtin_nontemporal_load((const long long*)(rec + i + u));
    uint4 q[16];
#pragma unroll
    for (int u = 0; u < 16; ++u) {
      uint32_t off = (u < n) ? (uint32_t)r[u] : 0u;   // clamp over-read addr
      q[u] = *(const uint4*)(sl + off);
    }
#pragma unroll
    for (int u = 0; u < 16; ++u) {
      uint32_t w = (uint32_t)((unsigned long long)r[u] >> 32);
      float v = VS ? bfhi(w) : bflo(w);
      v = (u < n) ? v : 0.0f;                         // mask over-read value
      if (u & 1) { FMA8(b0, b1, v, q[u]) } else { FMA8(a0, a1, v, q[u]) }
    }
  }
  A0 = make_float4(a0.x + b0.x, a0.y + b0.y, a0.z + b0.z, a0.w + b0.w);
  A1 = make_float4(a1.x + b1.x, a1.y + b1.y, a1.z + b1.z, a1.w + b1.w);
}

__device__ __forceinline__ float4 lk4(float4 x) {
  x.x = x.x >= 0.0f ? x.x : 0.5f * x.x;
  x.y = x.y >= 0.0f ? x.y : 0.5f * x.y;
  x.z = x.z >= 0.0f ? x.z : 0.5f * x.z;
  x.w = x.w >= 0.0f ? x.w : 0.5f * x.w;
  return x;
}

__device__ __forceinline__ uint4 pack8(float4 a, float4 b) {
  uint4 p;
  p.x = f2bf(a.x) | (f2bf(a.y) << 16);
  p.y = f2bf(a.z) | (f2bf(a.w) << 16);
  p.z = f2bf(b.x) | (f2bf(b.y) << 16);
  p.w = f2bf(b.z) | (f2bf(b.w) << 16);
  return p;
}

// Mega gather; grid covers NN rows (+TAG_N virtual rows when WITHTAG).
// r < NN:  o = leaky(adj) + (r<USER ? leaky(soc) : leaky(tag item row))
//   FINAL=false: latOut(bf16) = o
//   FINAL=true : acc(f32) = embed_f32(r) + f32(lat[r]) + o  (uE/iE direct;
//                acc is write-only — it doubled as stage1 during the build)
// r >= NN (WITHTAG only): rr = r-NN; tgOut[rr] = leaky(tag row ITEM_N+rr)
// Tag source region = lat + USER_N*DD is CONTIGUOUS [items][tags] by layout.
template <int VS, bool FINAL, bool WITHTAG>
__global__ void gather_mega_kernel(
    const int* __restrict__ arp, const int2* __restrict__ arec,
    const int* __restrict__ srp, const int2* __restrict__ srec,
    const int* __restrict__ trp, const int2* __restrict__ trec,
    const ushort* __restrict__ lat,   // NN x 64 bf16 (tag rows follow it)
    const float* __restrict__ uE, const float* __restrict__ iE,
    ushort* __restrict__ latOut, ushort* __restrict__ tgOut,
    float* __restrict__ acc) {
  int r = (blockIdx.x * blockDim.x + threadIdx.x) >> 3;
  int fl = threadIdx.x & 7;
  if (WITHTAG && r >= NN) {
    int rr = r - NN;
    if (rr >= TAG_N) return;
    int tr = rr + ITEM_N;
    float4 a0, a1;
    gather_sub<VS>(trp[tr], trp[tr + 1], trec, lat + (size_t)USER_N * DD, fl, a0, a1);
    ((uint4*)(tgOut + (size_t)rr * DD))[fl] = pack8(lk4(a0), lk4(a1));
    return;
  }
  if (r >= NN) return;
  float4 t0, t1, b0, b1;
  gather_sub<VS>(arp[r], arp[r + 1], arec, lat, fl, t0, t1);
  if (r < USER_N) {
    gather_sub<VS>(srp[r], srp[r + 1], srec, lat, fl, b0, b1);
  } else {
    int tr = r - USER_N;
    gather_sub<VS>(trp[tr], trp[tr + 1], trec, lat + (size_t)USER_N * DD, fl, b0, b1);
  }
  t0 = lk4(t0); t1 = lk4(t1); b0 = lk4(b0); b1 = lk4(b1);
  float4 o0 = make_float4(t0.x + b0.x, t0.y + b0.y, t0.z + b0.z, t0.w + b0.w);
  float4 o1 = make_float4(t1.x + b1.x, t1.y + b1.y, t1.z + b1.z, t1.w + b1.w);
  if (FINAL) {
    uint4 l = ((const uint4*)(lat + (size_t)r * DD))[fl];
    const float4* e0 = (r < USER_N)
        ? (const float4*)(uE + (size_t)r * DD)
        : (const float4*)(iE + (size_t)(r - USER_N) * DD);
    float4 v0 = e0[fl * 2], v1 = e0[fl * 2 + 1];
    v0.x += bflo(l.x) + o0.x; v0.y += bfhi(l.x) + o0.y;
    v0.z += bflo(l.y) + o0.z; v0.w += bfhi(l.y) + o0.w;
    v1.x += bflo(l.z) + o1.x; v1.y += bfhi(l.z) + o1.y;
    v1.z += bflo(l.w) + o1.z; v1.w += bfhi(l.w) + o1.w;
    float4* ap = (float4*)(acc + (size_t)r * DD);
    ap[fl * 2] = v0; ap[fl * 2 + 1] = v1;
  } else {
    ((uint4*)(latOut + (size_t)r * DD))[fl] = pack8(o0, o1);
  }
}

extern "C" void kernel_launch(void* const* d_in, const int* in_sizes, int n_in,
                              void* d_out, int out_size, void* d_ws, size_t ws_size,
                              hipStream_t stream) {
  const float* uE    = (const float*)d_in[0];
  const float* iE    = (const float*)d_in[1];
  const float* tEm   = (const float*)d_in[2];
  const int*   adj_r = (const int*)d_in[3];
  const int*   adj_c = (const int*)d_in[4];
  const float* adj_v = (const float*)d_in[5];
  const int*   tag_r = (const int*)d_in[6];
  const int*   tag_c = (const int*)d_in[7];
  const float* tag_v = (const float*)d_in[8];
  const int*   soc_r = (const int*)d_in[9];
  const int*   soc_c = (const int*)d_in[10];
  const float* soc_v = (const float*)d_in[11];
  const int nAdj = in_sizes[5], nTag = in_sizes[8], nSoc = in_sizes[11];
  const int totE = nAdj + nTag + nSoc;

  float* acc = (float*)d_out;

  // Workspace (~78 MB). bf16 regions: [lat0 items][tEmbf] and [lat1][tg1bf]
  // contiguous (tag-gather single-base requirement). Build-phase aliases:
  // stage0 -> lat1bf region (nAdj recs <= 2.72M cap; dead until mega0);
  // stage1 -> d_out (nTag+nSoc recs = 16 MB <= 38.4 MB; acc written only
  // by mega1). rec has 16 slack entries for the gather's 16-chunk over-read.
  ushort* lat0bf = (ushort*)d_ws;                  // NN*DD bf16
  ushort* tEmbf  = lat0bf + (size_t)NN * DD;       // TAG_N*DD (follows lat0!)
  ushort* lat1bf = tEmbf  + (size_t)TAG_N * DD;    // NN*DD
  ushort* tg1bf  = lat1bf + (size_t)NN * DD;       // TAG_N*DD (follows lat1!)
  int2* stage0   = (int2*)lat1bf;                  // alias (dead until mega0)
  int2* stage1   = (int2*)d_out;                   // alias (dead until mega1)
  int2* rec  = (int2*)(tg1bf + (size_t)TAG_N * DD);   // totE+16 {col*DD, pk}
  int*  ip   = (int*)(rec + totE + 16);
  int* chist = ip;  ip += NBKT * SLICES;           // per (bucket, slice) counts
  int* boff  = ip;  ip += NBKT * SLICES;           // per (bucket, slice) offsets
  int* btot  = ip;  ip += NBKT;
  int* bbase = ip;  ip += NBKT;
  int* rp    = ip;  ip += NT_ROWS + 1;

  // fold_in(key(42), j) for j=0..5 (host-side, deterministic)
  uint32_t kk[6][2];
  for (uint32_t j = 0; j < 6; ++j) tf2x32(0u, 42u, 0u, j, &kk[j][0], &kk[j][1]);

  const int thr = 256;
#define CDIV(a, b) (((a) + (b) - 1) / (b))

  // ---- CSR build: histinit, scanA, scanB, bin01, ls01 (5 dispatches) ----
  int initBlocks = CDIV((NN + TAG_N) * 16, 1024);
  histinit_kernel<<<2 * SLICES + initBlocks, 1024, 0, stream>>>(
      adj_r, tag_r, soc_r, chist, nAdj, nTag, nSoc,
      (const float4*)uE, (const float4*)iE, (const float4*)tEm,
      (ushort4*)lat0bf, (ushort4*)tEmbf);
  scanA_kernel<<<NBKT, 512, 0, stream>>>(chist, btot);
  scanB_kernel<<<NBKT, 512, 0, stream>>>(chist, btot, boff, bbase, rp, totE);
  bin01_kernel<<<2 * SLICES, 1024, 0, stream>>>(
      adj_r, adj_c, adj_v, tag_r, tag_c, tag_v, soc_r, soc_c, soc_v,
      boff, stage0, stage1, nAdj, nTag, nSoc,
      kk[0][0], kk[0][1], kk[3][0], kk[3][1],
      kk[1][0], kk[1][1], kk[4][0], kk[4][1],
      kk[2][0], kk[2][1], kk[5][0], kk[5][1]);
  ls01_kernel<<<NBKT, 512, 0, stream>>>(rp, bbase, btot, stage0, stage1, rec, nAdj);

  // ---- layer 0 (tag-node rows fused into the same launch) ----
  const int* arp = rp;
  const int* trp = rp + NN;
  const int* srp = rp + NN + MM;
  gather_mega_kernel<0, false, true><<<CDIV((NN + TAG_N) * 8, thr), thr, 0, stream>>>(
      arp, rec, srp, rec, trp, rec, lat0bf, uE, iE, lat1bf, tg1bf, nullptr);

  // ---- layer 1 ----
  gather_mega_kernel<1, true, false><<<CDIV(NN * 8, thr), thr, 0, stream>>>(
      arp, rec, srp, rec, trp, rec, lat1bf, uE, iE, nullptr, nullptr, acc);
#undef CDIV
}